// Round 1
// baseline (744.113 us; speedup 1.0000x reference)
//
#include <hip/hip_runtime.h>

// Problem constants
#define NB   16
#define NQ   300
#define ND   256
#define NH   8
#define NP   4
#define NF   2048
#define NHW  10000
#define NWG  100
#define NROW 4800          // NB*NQ

typedef __attribute__((ext_vector_type(8))) short bf16x8;
typedef __attribute__((ext_vector_type(4))) float f32x4;

__device__ __forceinline__ unsigned short f2bf(float f) {
    unsigned u = __builtin_bit_cast(unsigned, f);
    u = (u + 0x7fffu + ((u >> 16) & 1u)) >> 16;   // RNE
    return (unsigned short)u;
}
__device__ __forceinline__ float bf2f(unsigned short h) {
    unsigned u = ((unsigned)h) << 16;
    return __builtin_bit_cast(float, u);
}

// ---------------------------------------------------------------------------
// Weight prep: transpose fp32 [K][N] -> bf16 [N][K] for all six GEMM weights.
// Output-indexed (coalesced 2B writes; scattered 4B reads hit L2/LLC).
// ---------------------------------------------------------------------------
__global__ __launch_bounds__(256) void prep_weights(
    const float* __restrict__ w_in,  const float* __restrict__ w_out,
    const float* __restrict__ w_vp,  const float* __restrict__ w_op,
    const float* __restrict__ w_l1,  const float* __restrict__ w_l2,
    unsigned short* __restrict__ o_in, unsigned short* __restrict__ o_out,
    unsigned short* __restrict__ o_vp, unsigned short* __restrict__ o_op,
    unsigned short* __restrict__ o_l1, unsigned short* __restrict__ o_l2)
{
    int id = blockIdx.x * 256 + threadIdx.x;
    if (id < 196608) {                       // in_proj: [256][768] -> [768][256]
        int n = id >> 8, k = id & 255;
        o_in[id] = f2bf(w_in[k * 768 + n]);  return;
    }
    id -= 196608;
    if (id < 65536) {                        // out_proj: [256][256]
        int n = id >> 8, k = id & 255;
        o_out[id] = f2bf(w_out[k * 256 + n]); return;
    }
    id -= 65536;
    if (id < 65536) {                        // vproj
        int n = id >> 8, k = id & 255;
        o_vp[id] = f2bf(w_vp[k * 256 + n]);  return;
    }
    id -= 65536;
    if (id < 65536) {                        // oproj
        int n = id >> 8, k = id & 255;
        o_op[id] = f2bf(w_op[k * 256 + n]);  return;
    }
    id -= 65536;
    if (id < 524288) {                       // lin1: [256][2048] -> [2048][256]
        int n = id >> 8, k = id & 255;
        o_l1[id] = f2bf(w_l1[k * 2048 + n]); return;
    }
    id -= 524288;
    {                                        // lin2: [2048][256] -> [256][2048]
        int n = id >> 11, k = id & 2047;
        o_l2[id] = f2bf(w_l2[k * 256 + n]);
    }
}

// ---------------------------------------------------------------------------
// bf16 MFMA GEMM: C[M,N] = A[M,K](fp32) * Bt[N,K](bf16)^T + bias, opt ReLU,
// fp32 or bf16 output. 128x128 tile, BK=32, 256 threads (4 waves, 64x64 each).
// LDS stride 40 shorts (80 B) -> conflict-optimal ds_read_b128.
// ---------------------------------------------------------------------------
template <int RELU, int OUTBF>
__global__ __launch_bounds__(256, 2) void gemm_bt(
    const float* __restrict__ A, const unsigned short* __restrict__ Bt,
    const float* __restrict__ bias, void* __restrict__ Cout,
    int M, int N, int K)
{
    __shared__ unsigned short As[128][40];
    __shared__ unsigned short Bs[128][40];
    const int t    = threadIdx.x;
    const long m0  = (long)blockIdx.y * 128;
    const int  n0  = blockIdx.x * 128;
    const int  sr  = t >> 1;            // staging row 0..127
    const int  sc  = (t & 1) << 4;      // staging col 0 or 16
    const int  wave = t >> 6, lane = t & 63;
    const int  wm  = (wave >> 1) << 6;  // wave row offset in tile
    const int  wn  = (wave & 1) << 6;   // wave col offset in tile
    const int  l16 = lane & 15, quad = lane >> 4;

    f32x4 acc[4][4] = {};

    const bool aOk = (m0 + sr) < M;
    const bool bOk = (n0 + sr) < N;
    const float* aBase          = A  + (m0 + sr) * (long)K + sc;
    const unsigned short* bBase = Bt + (long)(n0 + sr) * K + sc;

    for (int k0 = 0; k0 < K; k0 += 32) {
        unsigned short ta[16];
        if (aOk) {
            const float4* ap = (const float4*)(aBase + k0);
            #pragma unroll
            for (int i = 0; i < 4; i++) {
                float4 f = ap[i];
                ta[i * 4 + 0] = f2bf(f.x); ta[i * 4 + 1] = f2bf(f.y);
                ta[i * 4 + 2] = f2bf(f.z); ta[i * 4 + 3] = f2bf(f.w);
            }
        } else {
            #pragma unroll
            for (int i = 0; i < 16; i++) ta[i] = 0;
        }
        uint4 tb0, tb1;
        if (bOk) {
            const uint4* bp = (const uint4*)(bBase + k0);
            tb0 = bp[0]; tb1 = bp[1];
        } else {
            tb0 = make_uint4(0, 0, 0, 0); tb1 = tb0;
        }
        *(bf16x8*)&As[sr][sc]     = *(bf16x8*)&ta[0];
        *(bf16x8*)&As[sr][sc + 8] = *(bf16x8*)&ta[8];
        *(uint4*)&Bs[sr][sc]      = tb0;
        *(uint4*)&Bs[sr][sc + 8]  = tb1;
        __syncthreads();

        bf16x8 af[4], bfr[4];
        #pragma unroll
        for (int i = 0; i < 4; i++)
            af[i] = *(const bf16x8*)&As[wm + i * 16 + l16][quad * 8];
        #pragma unroll
        for (int j = 0; j < 4; j++)
            bfr[j] = *(const bf16x8*)&Bs[wn + j * 16 + l16][quad * 8];
        #pragma unroll
        for (int i = 0; i < 4; i++)
            #pragma unroll
            for (int j = 0; j < 4; j++)
                acc[i][j] = __builtin_amdgcn_mfma_f32_16x16x32_bf16(
                    af[i], bfr[j], acc[i][j], 0, 0, 0);
        __syncthreads();
    }

    #pragma unroll
    for (int i = 0; i < 4; i++) {
        #pragma unroll
        for (int j = 0; j < 4; j++) {
            #pragma unroll
            for (int r = 0; r < 4; r++) {
                long gr = m0 + wm + i * 16 + quad * 4 + r;
                int  gc = n0 + wn + j * 16 + l16;
                if (gr < M) {
                    float v = acc[i][j][r] + bias[gc];
                    if (RELU) v = fmaxf(v, 0.0f);
                    if (OUTBF) ((unsigned short*)Cout)[gr * N + gc] = f2bf(v);
                    else       ((float*)Cout)[gr * N + gc] = v;
                }
            }
        }
    }
}

// ---------------------------------------------------------------------------
// Self-attention, one block per (b, h, half-of-Q). K/V staged as bf16 in LDS.
// Each wave handles q-rows independently; attn row passes via per-wave LDS
// (same-wave DS ops are in-order -> no barrier needed inside the q loop).
// ---------------------------------------------------------------------------
__global__ __launch_bounds__(256) void attn_kernel(
    const float* __restrict__ qkv, float* __restrict__ sa)
{
    __shared__ unsigned short Ks[NQ][40];
    __shared__ unsigned short Vs[NQ][40];
    __shared__ float attn_s[4][304];
    const int blk  = blockIdx.x;        // 0..255
    const int part = blk & 1;
    const int bh   = blk >> 1;
    const int b    = bh >> 3, h = bh & 7;
    const int t    = threadIdx.x;

    for (int idx = t; idx < NQ * 8; idx += 256) {
        int r = idx >> 3, c4 = (idx & 7) << 2;
        const float* kp = qkv + ((long)(b * NQ + r)) * 768 + 256 + h * 32 + c4;
        float4 kv = *(const float4*)kp;
        float4 vv = *(const float4*)(kp + 256);
        Ks[r][c4 + 0] = f2bf(kv.x); Ks[r][c4 + 1] = f2bf(kv.y);
        Ks[r][c4 + 2] = f2bf(kv.z); Ks[r][c4 + 3] = f2bf(kv.w);
        Vs[r][c4 + 0] = f2bf(vv.x); Vs[r][c4 + 1] = f2bf(vv.y);
        Vs[r][c4 + 2] = f2bf(vv.z); Vs[r][c4 + 3] = f2bf(vv.w);
    }
    __syncthreads();

    const int wave = t >> 6, lane = t & 63;
    const int l16 = lane & 15, g = lane >> 4;
    const float scale = 0.1767766952966369f;  // 1/sqrt(32)

    const int qBeg = part * 150, qEnd = qBeg + 150;
    for (int q = qBeg + wave; q < qEnd; q += 4) {
        const float* qp = qkv + ((long)(b * NQ + q)) * 768 + h * 32;
        float qv[32];
        #pragma unroll
        for (int i = 0; i < 8; i++) {
            float4 f = ((const float4*)qp)[i];
            qv[i * 4 + 0] = f.x; qv[i * 4 + 1] = f.y;
            qv[i * 4 + 2] = f.z; qv[i * 4 + 3] = f.w;
        }
        float s[5];
        #pragma unroll
        for (int kk = 0; kk < 5; kk++) {
            int kr = kk * 64 + lane;
            if (kr < NQ) {
                float acc = 0.f;
                #pragma unroll
                for (int c = 0; c < 4; c++) {
                    bf16x8 k8 = *(const bf16x8*)&Ks[kr][c * 8];
                    #pragma unroll
                    for (int j = 0; j < 8; j++)
                        acc += bf2f((unsigned short)k8[j]) * qv[c * 8 + j];
                }
                s[kk] = acc * scale;
            } else s[kk] = -1e30f;
        }
        float m = fmaxf(fmaxf(fmaxf(s[0], s[1]), fmaxf(s[2], s[3])), s[4]);
        #pragma unroll
        for (int off = 32; off >= 1; off >>= 1) m = fmaxf(m, __shfl_xor(m, off));
        float e[5], sum = 0.f;
        #pragma unroll
        for (int kk = 0; kk < 5; kk++) { e[kk] = __expf(s[kk] - m); sum += e[kk]; }
        #pragma unroll
        for (int off = 32; off >= 1; off >>= 1) sum += __shfl_xor(sum, off);
        float inv = 1.0f / sum;
        #pragma unroll
        for (int kk = 0; kk < 5; kk++) {
            int kr = kk * 64 + lane;
            if (kr < NQ) attn_s[wave][kr] = e[kk] * inv;
        }
        // output: lane = (g, pair l16); each group g covers k = g mod 4
        float a0 = 0.f, a1 = 0.f;
        for (int k = g; k < NQ; k += 4) {
            float aw = attn_s[wave][k];
            unsigned pv = *(const unsigned*)&Vs[k][l16 * 2];
            a0 += aw * bf2f((unsigned short)(pv & 0xffff));
            a1 += aw * bf2f((unsigned short)(pv >> 16));
        }
        a0 += __shfl_xor(a0, 16); a1 += __shfl_xor(a1, 16);
        a0 += __shfl_xor(a0, 32); a1 += __shfl_xor(a1, 32);
        if (g == 0) {
            float2* op = (float2*)(sa + ((long)(b * NQ + q)) * ND + h * 32 + l16 * 2);
            *op = make_float2(a0, a1);
        }
    }
}

// ---------------------------------------------------------------------------
// Residual + LayerNorm: one wave per row of 256.
// ---------------------------------------------------------------------------
__global__ __launch_bounds__(256) void residual_ln(
    const float* __restrict__ a, const float* __restrict__ r,
    const float* __restrict__ gam, const float* __restrict__ bet,
    float* __restrict__ out)
{
    const int row  = blockIdx.x * 4 + (threadIdx.x >> 6);
    const int lane = threadIdx.x & 63;
    const long base = (long)row * ND + lane * 4;
    float4 av = *(const float4*)(a + base);
    float4 rv = *(const float4*)(r + base);
    float x0 = av.x + rv.x, x1 = av.y + rv.y, x2 = av.z + rv.z, x3 = av.w + rv.w;
    float s  = x0 + x1 + x2 + x3;
    float s2 = x0 * x0 + x1 * x1 + x2 * x2 + x3 * x3;
    #pragma unroll
    for (int off = 32; off >= 1; off >>= 1) {
        s  += __shfl_xor(s, off);
        s2 += __shfl_xor(s2, off);
    }
    float mean = s * 0.00390625f;
    float var  = s2 * 0.00390625f - mean * mean;
    float rstd = rsqrtf(var + 1e-5f);
    float4 gv = *(const float4*)(gam + lane * 4);
    float4 bv = *(const float4*)(bet + lane * 4);
    float4 o;
    o.x = (x0 - mean) * rstd * gv.x + bv.x;
    o.y = (x1 - mean) * rstd * gv.y + bv.y;
    o.z = (x2 - mean) * rstd * gv.z + bv.z;
    o.w = (x3 - mean) * rstd * gv.w + bv.w;
    *(float4*)(out + base) = o;
}

// ---------------------------------------------------------------------------
// ref/offsets/attw + sampling metadata. One block (128 thr) per (b,q) row.
// meta row = 256 floats: [h][p][ i00 i01 i10 i11 w00 w01 w10 w11 ],
// weights pre-multiplied by softmaxed attention weight.
// ---------------------------------------------------------------------------
__global__ __launch_bounds__(128) void head_prep(
    const float* __restrict__ x,
    const float* __restrict__ rw, const float* __restrict__ rb,
    const float* __restrict__ ow, const float* __restrict__ ob,
    const float* __restrict__ aw, const float* __restrict__ ab,
    float* __restrict__ meta)
{
    const int row = blockIdx.x;
    __shared__ float xs[256];
    __shared__ float res[98];
    const int t = threadIdx.x;
    xs[t]       = x[(long)row * ND + t];
    xs[t + 128] = x[(long)row * ND + 128 + t];
    __syncthreads();
    if (t < 98) {
        const float* wp; int stride; float acc;
        if (t < 2)       { wp = rw + t;        stride = 2;  acc = rb[t]; }
        else if (t < 66) { wp = ow + (t - 2);  stride = 64; acc = ob[t - 2]; }
        else             { wp = aw + (t - 66); stride = 32; acc = ab[t - 66]; }
        for (int k = 0; k < 256; k++) acc += xs[k] * wp[k * stride];
        res[t] = acc;
    }
    __syncthreads();
    if (t < 32) {
        const int h = t >> 2, p = t & 3;
        const float rx = 1.f / (1.f + __expf(-res[0]));
        const float ry = 1.f / (1.f + __expf(-res[1]));
        const float offx = res[2 + h * 8 + p * 2];
        const float offy = res[2 + h * 8 + p * 2 + 1];
        const float a0 = res[66 + h * 4 + 0], a1 = res[66 + h * 4 + 1];
        const float a2 = res[66 + h * 4 + 2], a3 = res[66 + h * 4 + 3];
        const float mx = fmaxf(fmaxf(a0, a1), fmaxf(a2, a3));
        const float den = __expf(a0 - mx) + __expf(a1 - mx) +
                          __expf(a2 - mx) + __expf(a3 - mx);
        const float awt = __expf(res[66 + h * 4 + p] - mx) / den;

        const float lx = fminf(fmaxf(rx + offx, 0.f), 1.f) * (NWG - 1);
        const float ly = fminf(fmaxf(ry + offy, 0.f), 1.f) * (NWG - 1);
        const float fx = floorf(lx), fy = floorf(ly);
        int x0 = (int)fx; x0 = min(max(x0, 0), NWG - 1);
        int y0 = (int)fy; y0 = min(max(y0, 0), NWG - 1);
        const int x1 = min(x0 + 1, NWG - 1);
        const int y1 = min(y0 + 1, NWG - 1);
        const float wx1 = lx - fx, wx0 = 1.f - wx1;
        const float wy1 = ly - fy, wy0 = 1.f - wy1;
        float* mp = meta + (long)row * 256 + t * 8;
        mp[0] = __int_as_float(y0 * NWG + x0);
        mp[1] = __int_as_float(y0 * NWG + x1);
        mp[2] = __int_as_float(y1 * NWG + x0);
        mp[3] = __int_as_float(y1 * NWG + x1);
        mp[4] = awt * wx0 * wy0;
        mp[5] = awt * wx1 * wy0;
        mp[6] = awt * wx0 * wy1;
        mp[7] = awt * wx1 * wy1;
    }
}

// ---------------------------------------------------------------------------
// Deformable gather: block per (b,q); thread (h = t>>5, d = t&31).
// ---------------------------------------------------------------------------
__global__ __launch_bounds__(256) void deform_gather(
    const float* __restrict__ meta, const unsigned short* __restrict__ vals,
    float* __restrict__ ca)
{
    const int row = blockIdx.x;           // b*300+q
    const int b = row / NQ;
    __shared__ float ms[256];
    const int t = threadIdx.x;
    ms[t] = meta[(long)row * 256 + t];
    __syncthreads();
    const int h = t >> 5, d = t & 31;
    const unsigned short* vb = vals + (long)b * NHW * ND + h * 32 + d;
    float acc = 0.f;
    #pragma unroll
    for (int p = 0; p < NP; p++) {
        const float* mp = ms + h * 32 + p * 8;
        const int i00 = __float_as_int(mp[0]);
        const int i01 = __float_as_int(mp[1]);
        const int i10 = __float_as_int(mp[2]);
        const int i11 = __float_as_int(mp[3]);
        acc += mp[4] * bf2f(vb[(long)i00 * ND]);
        acc += mp[5] * bf2f(vb[(long)i01 * ND]);
        acc += mp[6] * bf2f(vb[(long)i10 * ND]);
        acc += mp[7] * bf2f(vb[(long)i11 * ND]);
    }
    ca[(long)row * ND + t] = acc;
}

// ---------------------------------------------------------------------------
extern "C" void kernel_launch(void* const* d_in, const int* in_sizes, int n_in,
                              void* d_out, int out_size, void* d_ws, size_t ws_size,
                              hipStream_t stream)
{
    (void)in_sizes; (void)n_in; (void)out_size; (void)ws_size;
    const float* tgt   = (const float*)d_in[0];
    const float* mem   = (const float*)d_in[1];
    const float* inpw  = (const float*)d_in[2];
    const float* inpb  = (const float*)d_in[3];
    const float* outw  = (const float*)d_in[4];
    const float* outb  = (const float*)d_in[5];
    const float* n1g   = (const float*)d_in[6];
    const float* n1b   = (const float*)d_in[7];
    const float* refw  = (const float*)d_in[8];
    const float* refb  = (const float*)d_in[9];
    const float* offw  = (const float*)d_in[10];
    const float* offb  = (const float*)d_in[11];
    const float* attww = (const float*)d_in[12];
    const float* attwb = (const float*)d_in[13];
    const float* vpw   = (const float*)d_in[14];
    const float* vpb   = (const float*)d_in[15];
    const float* opw   = (const float*)d_in[16];
    const float* opb   = (const float*)d_in[17];
    const float* n2g   = (const float*)d_in[18];
    const float* n2b   = (const float*)d_in[19];
    const float* l1w   = (const float*)d_in[20];
    const float* l1b   = (const float*)d_in[21];
    const float* l2w   = (const float*)d_in[22];
    const float* l2b   = (const float*)d_in[23];
    const float* n3g   = (const float*)d_in[24];
    const float* n3b   = (const float*)d_in[25];
    float* out = (float*)d_out;

    // workspace carve-out (~129.3 MB total)
    char* p = (char*)d_ws;
    auto alloc = [&](size_t bytes) {
        char* r = p; p += (bytes + 255) & ~(size_t)255; return (void*)r;
    };
    unsigned short* wtIn  = (unsigned short*)alloc(768 * 256 * 2);
    unsigned short* wtOut = (unsigned short*)alloc(256 * 256 * 2);
    unsigned short* wtVp  = (unsigned short*)alloc(256 * 256 * 2);
    unsigned short* wtOp  = (unsigned short*)alloc(256 * 256 * 2);
    unsigned short* wtL1  = (unsigned short*)alloc(2048 * 256 * 2);
    unsigned short* wtL2  = (unsigned short*)alloc(256 * 2048 * 2);
    float* qkv  = (float*)alloc((size_t)NROW * 768 * 4);
    float* sa   = (float*)alloc((size_t)NROW * ND * 4);
    float* x1   = (float*)alloc((size_t)NROW * ND * 4);
    float* x2   = (float*)alloc((size_t)NROW * ND * 4);
    float* tmp  = (float*)alloc((size_t)NROW * ND * 4);
    float* ca   = (float*)alloc((size_t)NROW * ND * 4);
    float* meta = (float*)alloc((size_t)NROW * 256 * 4);
    // vals (bf16, 82 MB) is dead after deform_gather; h1 (fp32, 39 MB) reuses it
    void* uni = alloc((size_t)NB * NHW * ND * 2);
    unsigned short* vals = (unsigned short*)uni;
    float* h1 = (float*)uni;

    prep_weights<<<5632, 256, 0, stream>>>(inpw, outw, vpw, opw, l1w, l2w,
                                           wtIn, wtOut, wtVp, wtOp, wtL1, wtL2);
    // qkv = tgt @ in_proj + b
    gemm_bt<0, 0><<<dim3(6, 38), 256, 0, stream>>>(tgt, wtIn, inpb, qkv,
                                                   NROW, 768, 256);
    // vals = memory @ vproj + b   (bf16 out) — independent, issue early
    gemm_bt<0, 1><<<dim3(2, 1250), 256, 0, stream>>>(mem, wtVp, vpb, vals,
                                                     NB * NHW, 256, 256);
    attn_kernel<<<256, 256, 0, stream>>>(qkv, sa);
    gemm_bt<0, 0><<<dim3(2, 38), 256, 0, stream>>>(sa, wtOut, outb, tmp,
                                                   NROW, 256, 256);
    residual_ln<<<1200, 256, 0, stream>>>(tgt, tmp, n1g, n1b, x1);
    head_prep<<<4800, 128, 0, stream>>>(x1, refw, refb, offw, offb,
                                        attww, attwb, meta);
    deform_gather<<<4800, 256, 0, stream>>>(meta, vals, ca);
    gemm_bt<0, 0><<<dim3(2, 38), 256, 0, stream>>>(ca, wtOp, opb, tmp,
                                                   NROW, 256, 256);
    residual_ln<<<1200, 256, 0, stream>>>(x1, tmp, n2g, n2b, x2);
    gemm_bt<1, 0><<<dim3(16, 38), 256, 0, stream>>>(x2, wtL1, l1b, h1,
                                                    NROW, 2048, 256);
    gemm_bt<0, 0><<<dim3(2, 38), 256, 0, stream>>>(h1, wtL2, l2b, tmp,
                                                   NROW, 256, 2048);
    residual_ln<<<1200, 256, 0, stream>>>(x2, tmp, n3g, n3b, out);
}

// Round 2
// 681.855 us; speedup vs baseline: 1.0913x; 1.0913x over previous
//
#include <hip/hip_runtime.h>

// Problem constants
#define NB   16
#define NQ   300
#define ND   256
#define NH   8
#define NP   4
#define NF   2048
#define NHW  10000
#define NWG  100
#define NROW 4800          // NB*NQ

typedef __attribute__((ext_vector_type(8))) short bf16x8;
typedef __attribute__((ext_vector_type(4))) float f32x4;

__device__ __forceinline__ unsigned short f2bf(float f) {
    unsigned u = __builtin_bit_cast(unsigned, f);
    u = (u + 0x7fffu + ((u >> 16) & 1u)) >> 16;   // RNE
    return (unsigned short)u;
}
__device__ __forceinline__ float bf2f(unsigned short h) {
    unsigned u = ((unsigned)h) << 16;
    return __builtin_bit_cast(float, u);
}

// ---------------------------------------------------------------------------
// Weight prep: transpose fp32 [K][N] -> bf16 [N][K] for GEMM weights, plus
// the concatenated head weight [128][256] (ref 2 | off 64 | attw 32 | pad 30)
// and its fp32 bias[128].
// ---------------------------------------------------------------------------
__global__ __launch_bounds__(256) void prep_weights(
    const float* __restrict__ w_in,  const float* __restrict__ w_out,
    const float* __restrict__ w_vp,  const float* __restrict__ w_op,
    const float* __restrict__ w_l1,  const float* __restrict__ w_l2,
    const float* __restrict__ rw, const float* __restrict__ rb,
    const float* __restrict__ ow, const float* __restrict__ ob,
    const float* __restrict__ aw, const float* __restrict__ ab,
    unsigned short* __restrict__ o_in, unsigned short* __restrict__ o_out,
    unsigned short* __restrict__ o_vp, unsigned short* __restrict__ o_op,
    unsigned short* __restrict__ o_l1, unsigned short* __restrict__ o_l2,
    unsigned short* __restrict__ o_hd, float* __restrict__ o_hb)
{
    int id = blockIdx.x * 256 + threadIdx.x;
    if (id < 196608) {                       // in_proj: [256][768] -> [768][256]
        int n = id >> 8, k = id & 255;
        o_in[id] = f2bf(w_in[k * 768 + n]);  return;
    }
    id -= 196608;
    if (id < 65536) {                        // out_proj
        int n = id >> 8, k = id & 255;
        o_out[id] = f2bf(w_out[k * 256 + n]); return;
    }
    id -= 65536;
    if (id < 65536) {                        // vproj
        int n = id >> 8, k = id & 255;
        o_vp[id] = f2bf(w_vp[k * 256 + n]);  return;
    }
    id -= 65536;
    if (id < 65536) {                        // oproj
        int n = id >> 8, k = id & 255;
        o_op[id] = f2bf(w_op[k * 256 + n]);  return;
    }
    id -= 65536;
    if (id < 524288) {                       // lin1: [256][2048] -> [2048][256]
        int n = id >> 8, k = id & 255;
        o_l1[id] = f2bf(w_l1[k * 2048 + n]); return;
    }
    id -= 524288;
    if (id < 524288) {                       // lin2: [2048][256] -> [256][2048]
        int n = id >> 11, k = id & 2047;
        o_l2[id] = f2bf(w_l2[k * 256 + n]);  return;
    }
    id -= 524288;
    if (id < 32768) {                        // head concat weight [128][256]
        int n = id >> 8, k = id & 255;
        float v;
        if (n < 2)       v = rw[k * 2 + n];
        else if (n < 66) v = ow[k * 64 + (n - 2)];
        else if (n < 98) v = aw[k * 32 + (n - 66)];
        else             v = 0.0f;
        o_hd[id] = f2bf(v);                  return;
    }
    id -= 32768;
    if (id < 128) {                          // head bias
        float v;
        if (id < 2)       v = rb[id];
        else if (id < 66) v = ob[id - 2];
        else if (id < 98) v = ab[id - 66];
        else              v = 0.0f;
        o_hb[id] = v;
    }
}

// ---------------------------------------------------------------------------
// bf16 MFMA GEMM: C[M,N] = A[M,K](fp32) * Bt[N,K](bf16)^T + bias, opt ReLU,
// fp32 or bf16 output. Tile 128 x (128*NT), BK=32, 256 threads (4 waves).
// NT=2 halves A re-reads (each block covers 256 N-columns).
// ---------------------------------------------------------------------------
template <int RELU, int OUTBF, int NT>
__global__ __launch_bounds__(256, 2) void gemm_bt(
    const float* __restrict__ A, const unsigned short* __restrict__ Bt,
    const float* __restrict__ bias, void* __restrict__ Cout,
    int M, int N, int K)
{
    __shared__ unsigned short As[128][40];
    __shared__ unsigned short Bs[128 * NT][40];
    const int t    = threadIdx.x;
    const long m0  = (long)blockIdx.y * 128;
    const int  n0  = blockIdx.x * (128 * NT);
    const int  sr  = t >> 1;            // staging row 0..127
    const int  sc  = (t & 1) << 4;      // staging col 0 or 16
    const int  wave = t >> 6, lane = t & 63;
    const int  wm  = (wave >> 1) << 6;
    const int  wn  = (wave & 1) * (64 * NT);
    const int  l16 = lane & 15, quad = lane >> 4;

    f32x4 acc[4][4 * NT] = {};

    const bool aOk = (m0 + sr) < M;
    const float* aBase = A + (m0 + sr) * (long)K + sc;

    for (int k0 = 0; k0 < K; k0 += 32) {
        unsigned short ta[16];
        if (aOk) {
            const float4* ap = (const float4*)(aBase + k0);
            #pragma unroll
            for (int i = 0; i < 4; i++) {
                float4 f = ap[i];
                ta[i * 4 + 0] = f2bf(f.x); ta[i * 4 + 1] = f2bf(f.y);
                ta[i * 4 + 2] = f2bf(f.z); ta[i * 4 + 3] = f2bf(f.w);
            }
        } else {
            #pragma unroll
            for (int i = 0; i < 16; i++) ta[i] = 0;
        }
        *(bf16x8*)&As[sr][sc]     = *(bf16x8*)&ta[0];
        *(bf16x8*)&As[sr][sc + 8] = *(bf16x8*)&ta[8];
        #pragma unroll
        for (int rep = 0; rep < NT; rep++) {
            const int row = sr + rep * 128;
            uint4 tb0, tb1;
            if (n0 + row < N) {
                const uint4* bp = (const uint4*)(Bt + (long)(n0 + row) * K + sc + k0);
                tb0 = bp[0]; tb1 = bp[1];
            } else {
                tb0 = make_uint4(0, 0, 0, 0); tb1 = tb0;
            }
            *(uint4*)&Bs[row][sc]     = tb0;
            *(uint4*)&Bs[row][sc + 8] = tb1;
        }
        __syncthreads();

        bf16x8 af[4], bfr[4 * NT];
        #pragma unroll
        for (int i = 0; i < 4; i++)
            af[i] = *(const bf16x8*)&As[wm + i * 16 + l16][quad * 8];
        #pragma unroll
        for (int j = 0; j < 4 * NT; j++)
            bfr[j] = *(const bf16x8*)&Bs[wn + j * 16 + l16][quad * 8];
        #pragma unroll
        for (int i = 0; i < 4; i++)
            #pragma unroll
            for (int j = 0; j < 4 * NT; j++)
                acc[i][j] = __builtin_amdgcn_mfma_f32_16x16x32_bf16(
                    af[i], bfr[j], acc[i][j], 0, 0, 0);
        __syncthreads();
    }

    #pragma unroll
    for (int i = 0; i < 4; i++) {
        #pragma unroll
        for (int j = 0; j < 4 * NT; j++) {
            #pragma unroll
            for (int r = 0; r < 4; r++) {
                long gr = m0 + wm + i * 16 + quad * 4 + r;
                int  gc = n0 + wn + j * 16 + l16;
                if (gr < M) {
                    float v = acc[i][j][r] + bias[gc];
                    if (RELU) v = fmaxf(v, 0.0f);
                    if (OUTBF) ((unsigned short*)Cout)[gr * N + gc] = f2bf(v);
                    else       ((float*)Cout)[gr * N + gc] = v;
                }
            }
        }
    }
}

// ---------------------------------------------------------------------------
// MFMA self-attention. Grid (5 q-tiles, 128 b*h). Block = 256 thr = 4 waves;
// wave w owns q-rows [q0+16w, q0+16w+16).
// S = Q(16x32) @ K^T via 19 MFMAs; softmax in-register (row r lives in quad
// group r>>2); P round-trips LDS (bf16) into A-layout; O = P @ V via 20 MFMAs
// with V stored transposed. Ps aliases Ks/Qs (union) -> 63 KB static LDS.
// ---------------------------------------------------------------------------
__global__ __launch_bounds__(256) void attn_kernel(
    const float* __restrict__ qkv, float* __restrict__ sa)
{
    __shared__ union {
        struct {
            unsigned short Ks[304][40];   // 24,320 B
            unsigned short Qs[64][40];    //  5,120 B
        } s;
        unsigned short Ps[4][16][328];    // 41,984 B
    } u;
    __shared__ unsigned short Vt[32][328]; // 20,992 B  (total 62,976 B)

    const int bh = blockIdx.y;            // b*8 + h
    const int b  = bh >> 3, h = bh & 7;
    const int q0 = blockIdx.x * 64;
    const int t  = threadIdx.x;

    // ---- stage K rows 0..299 (zero 300..303)
    for (int idx = t; idx < 304 * 8; idx += 256) {
        const int r = idx >> 3, c4 = (idx & 7) << 2;
        if (r < NQ) {
            const float4 kv = *(const float4*)(qkv + ((long)(b * NQ + r)) * 768 + 256 + h * 32 + c4);
            u.s.Ks[r][c4 + 0] = f2bf(kv.x); u.s.Ks[r][c4 + 1] = f2bf(kv.y);
            u.s.Ks[r][c4 + 2] = f2bf(kv.z); u.s.Ks[r][c4 + 3] = f2bf(kv.w);
        } else {
            u.s.Ks[r][c4 + 0] = 0; u.s.Ks[r][c4 + 1] = 0;
            u.s.Ks[r][c4 + 2] = 0; u.s.Ks[r][c4 + 3] = 0;
        }
    }
    // ---- stage V transposed: Vt[d][key]
    for (int idx = t; idx < NQ * 8; idx += 256) {
        const int key = idx >> 3, dq = (idx & 7) << 2;
        const float4 vv = *(const float4*)(qkv + ((long)(b * NQ + key)) * 768 + 512 + h * 32 + dq);
        Vt[dq + 0][key] = f2bf(vv.x); Vt[dq + 1][key] = f2bf(vv.y);
        Vt[dq + 2][key] = f2bf(vv.z); Vt[dq + 3][key] = f2bf(vv.w);
    }
    for (int idx = t; idx < 32 * 20; idx += 256)   // zero keys 300..319
        Vt[idx / 20][300 + idx % 20] = 0;
    // ---- stage Q tile rows q0..q0+63 (zero pad)
    for (int idx = t; idx < 64 * 8; idx += 256) {
        const int r = idx >> 3, c4 = (idx & 7) << 2;
        const int q = q0 + r;
        if (q < NQ) {
            const float4 qv = *(const float4*)(qkv + ((long)(b * NQ + q)) * 768 + h * 32 + c4);
            u.s.Qs[r][c4 + 0] = f2bf(qv.x); u.s.Qs[r][c4 + 1] = f2bf(qv.y);
            u.s.Qs[r][c4 + 2] = f2bf(qv.z); u.s.Qs[r][c4 + 3] = f2bf(qv.w);
        } else {
            u.s.Qs[r][c4 + 0] = 0; u.s.Qs[r][c4 + 1] = 0;
            u.s.Qs[r][c4 + 2] = 0; u.s.Qs[r][c4 + 3] = 0;
        }
    }
    __syncthreads();

    const int wave = t >> 6, lane = t & 63;
    const int l16 = lane & 15, quad = lane >> 4;
    const float scale = 0.1767766952966369f;   // 1/sqrt(32)

    const bf16x8 aq = *(const bf16x8*)&u.s.Qs[wave * 16 + l16][quad * 8];
    f32x4 sacc[19];
    #pragma unroll
    for (int kt = 0; kt < 19; kt++) {
        const bf16x8 bk = *(const bf16x8*)&u.s.Ks[kt * 16 + l16][quad * 8];
        sacc[kt] = __builtin_amdgcn_mfma_f32_16x16x32_bf16(
            aq, bk, (f32x4){0.f, 0.f, 0.f, 0.f}, 0, 0, 0);
    }

    // softmax: row r=quad*4+reg spans keys kt*16+l16 across the quad group
    float inv[4];
    #pragma unroll
    for (int r = 0; r < 4; r++) {
        float m = -1e30f;
        #pragma unroll
        for (int kt = 0; kt < 19; kt++) {
            float s = sacc[kt][r] * scale;
            if (kt == 18 && l16 >= 12) s = -1e30f;    // keys 300..303 invalid
            sacc[kt][r] = s;
            m = fmaxf(m, s);
        }
        m = fmaxf(m, __shfl_xor(m, 1)); m = fmaxf(m, __shfl_xor(m, 2));
        m = fmaxf(m, __shfl_xor(m, 4)); m = fmaxf(m, __shfl_xor(m, 8));
        float sum = 0.f;
        #pragma unroll
        for (int kt = 0; kt < 19; kt++) {
            float p = __expf(sacc[kt][r] - m);
            sacc[kt][r] = p;
            sum += p;
        }
        sum += __shfl_xor(sum, 1); sum += __shfl_xor(sum, 2);
        sum += __shfl_xor(sum, 4); sum += __shfl_xor(sum, 8);
        inv[r] = 1.0f / sum;
    }

    __syncthreads();   // all waves done with Ks/Qs before Ps overwrites them

    #pragma unroll
    for (int kt = 0; kt < 19; kt++)
        #pragma unroll
        for (int r = 0; r < 4; r++)
            u.Ps[wave][quad * 4 + r][kt * 16 + l16] = f2bf(sacc[kt][r] * inv[r]);
    #pragma unroll
    for (int r = 0; r < 4; r++)      // zero pad keys 304..319
        u.Ps[wave][quad * 4 + r][304 + l16] = 0;

    f32x4 o0 = {0.f, 0.f, 0.f, 0.f}, o1 = {0.f, 0.f, 0.f, 0.f};
    #pragma unroll
    for (int kt = 0; kt < 10; kt++) {
        const bf16x8 ap  = *(const bf16x8*)&u.Ps[wave][l16][kt * 32 + quad * 8];
        const bf16x8 bv0 = *(const bf16x8*)&Vt[l16][kt * 32 + quad * 8];
        const bf16x8 bv1 = *(const bf16x8*)&Vt[16 + l16][kt * 32 + quad * 8];
        o0 = __builtin_amdgcn_mfma_f32_16x16x32_bf16(ap, bv0, o0, 0, 0, 0);
        o1 = __builtin_amdgcn_mfma_f32_16x16x32_bf16(ap, bv1, o1, 0, 0, 0);
    }

    #pragma unroll
    for (int r = 0; r < 4; r++) {
        const int q = q0 + wave * 16 + quad * 4 + r;
        if (q < NQ) {
            float* op = sa + ((long)(b * NQ + q)) * ND + h * 32;
            op[l16]      = o0[r];
            op[16 + l16] = o1[r];
        }
    }
}

// ---------------------------------------------------------------------------
// Residual + LayerNorm: one wave per row of 256.
// ---------------------------------------------------------------------------
__global__ __launch_bounds__(256) void residual_ln(
    const float* __restrict__ a, const float* __restrict__ r,
    const float* __restrict__ gam, const float* __restrict__ bet,
    float* __restrict__ out)
{
    const int row  = blockIdx.x * 4 + (threadIdx.x >> 6);
    const int lane = threadIdx.x & 63;
    const long base = (long)row * ND + lane * 4;
    float4 av = *(const float4*)(a + base);
    float4 rv = *(const float4*)(r + base);
    float x0 = av.x + rv.x, x1 = av.y + rv.y, x2 = av.z + rv.z, x3 = av.w + rv.w;
    float s  = x0 + x1 + x2 + x3;
    float s2 = x0 * x0 + x1 * x1 + x2 * x2 + x3 * x3;
    #pragma unroll
    for (int off = 32; off >= 1; off >>= 1) {
        s  += __shfl_xor(s, off);
        s2 += __shfl_xor(s2, off);
    }
    float mean = s * 0.00390625f;
    float var  = s2 * 0.00390625f - mean * mean;
    float rstd = rsqrtf(var + 1e-5f);
    float4 gv = *(const float4*)(gam + lane * 4);
    float4 bv = *(const float4*)(bet + lane * 4);
    float4 o;
    o.x = (x0 - mean) * rstd * gv.x + bv.x;
    o.y = (x1 - mean) * rstd * gv.y + bv.y;
    o.z = (x2 - mean) * rstd * gv.z + bv.z;
    o.w = (x3 - mean) * rstd * gv.w + bv.w;
    *(float4*)(out + base) = o;
}

// ---------------------------------------------------------------------------
// meta from head-GEMM result res[4800][128]:
// res[0:2]=ref logits, res[2:66]=offsets, res[66:98]=attw logits.
// 32 lanes per row; lane s=(h,p). meta row = [h][p][i00..i11 w00..w11].
// ---------------------------------------------------------------------------
__global__ __launch_bounds__(256) void meta_kernel(
    const float* __restrict__ res, float* __restrict__ meta)
{
    const int t   = threadIdx.x;
    const int row = blockIdx.x * 8 + (t >> 5);
    const int s   = t & 31;
    const int h   = s >> 2;
    const float* rp = res + (long)row * 128;
    const float rx = 1.f / (1.f + __expf(-rp[0]));
    const float ry = 1.f / (1.f + __expf(-rp[1]));
    const float offx = rp[2 + 2 * s], offy = rp[3 + 2 * s];
    const float a0 = rp[66 + h * 4 + 0], a1 = rp[66 + h * 4 + 1];
    const float a2 = rp[66 + h * 4 + 2], a3 = rp[66 + h * 4 + 3];
    const float mx = fmaxf(fmaxf(a0, a1), fmaxf(a2, a3));
    const float den = __expf(a0 - mx) + __expf(a1 - mx) +
                      __expf(a2 - mx) + __expf(a3 - mx);
    const float awt = __expf(rp[66 + s] - mx) / den;

    const float lx = fminf(fmaxf(rx + offx, 0.f), 1.f) * (NWG - 1);
    const float ly = fminf(fmaxf(ry + offy, 0.f), 1.f) * (NWG - 1);
    const float fx = floorf(lx), fy = floorf(ly);
    int x0 = (int)fx; x0 = min(max(x0, 0), NWG - 1);
    int y0 = (int)fy; y0 = min(max(y0, 0), NWG - 1);
    const int x1 = min(x0 + 1, NWG - 1);
    const int y1 = min(y0 + 1, NWG - 1);
    const float wx1 = lx - fx, wx0 = 1.f - wx1;
    const float wy1 = ly - fy, wy0 = 1.f - wy1;
    float4 m0, m1;
    m0.x = __int_as_float(y0 * NWG + x0);
    m0.y = __int_as_float(y0 * NWG + x1);
    m0.z = __int_as_float(y1 * NWG + x0);
    m0.w = __int_as_float(y1 * NWG + x1);
    m1.x = awt * wx0 * wy0;
    m1.y = awt * wx1 * wy0;
    m1.z = awt * wx0 * wy1;
    m1.w = awt * wx1 * wy1;
    float* mp = meta + (long)row * 256 + s * 8;
    *(float4*)mp       = m0;
    *(float4*)(mp + 4) = m1;
}

// ---------------------------------------------------------------------------
// Deformable gather: block per (b,q); thread (h = t>>5, d = t&31).
// ---------------------------------------------------------------------------
__global__ __launch_bounds__(256) void deform_gather(
    const float* __restrict__ meta, const unsigned short* __restrict__ vals,
    float* __restrict__ ca)
{
    const int row = blockIdx.x;           // b*300+q
    const int b = row / NQ;
    __shared__ float ms[256];
    const int t = threadIdx.x;
    ms[t] = meta[(long)row * 256 + t];
    __syncthreads();
    const int h = t >> 5, d = t & 31;
    const unsigned short* vb = vals + (long)b * NHW * ND + h * 32 + d;
    float acc = 0.f;
    #pragma unroll
    for (int p = 0; p < NP; p++) {
        const float* mp = ms + h * 32 + p * 8;
        const int i00 = __float_as_int(mp[0]);
        const int i01 = __float_as_int(mp[1]);
        const int i10 = __float_as_int(mp[2]);
        const int i11 = __float_as_int(mp[3]);
        acc += mp[4] * bf2f(vb[(long)i00 * ND]);
        acc += mp[5] * bf2f(vb[(long)i01 * ND]);
        acc += mp[6] * bf2f(vb[(long)i10 * ND]);
        acc += mp[7] * bf2f(vb[(long)i11 * ND]);
    }
    ca[(long)row * ND + t] = acc;
}

// ---------------------------------------------------------------------------
extern "C" void kernel_launch(void* const* d_in, const int* in_sizes, int n_in,
                              void* d_out, int out_size, void* d_ws, size_t ws_size,
                              hipStream_t stream)
{
    (void)in_sizes; (void)n_in; (void)out_size; (void)ws_size;
    const float* tgt   = (const float*)d_in[0];
    const float* mem   = (const float*)d_in[1];
    const float* inpw  = (const float*)d_in[2];
    const float* inpb  = (const float*)d_in[3];
    const float* outw  = (const float*)d_in[4];
    const float* outb  = (const float*)d_in[5];
    const float* n1g   = (const float*)d_in[6];
    const float* n1b   = (const float*)d_in[7];
    const float* refw  = (const float*)d_in[8];
    const float* refb  = (const float*)d_in[9];
    const float* offw  = (const float*)d_in[10];
    const float* offb  = (const float*)d_in[11];
    const float* attww = (const float*)d_in[12];
    const float* attwb = (const float*)d_in[13];
    const float* vpw   = (const float*)d_in[14];
    const float* vpb   = (const float*)d_in[15];
    const float* opw   = (const float*)d_in[16];
    const float* opb   = (const float*)d_in[17];
    const float* n2g   = (const float*)d_in[18];
    const float* n2b   = (const float*)d_in[19];
    const float* l1w   = (const float*)d_in[20];
    const float* l1b   = (const float*)d_in[21];
    const float* l2w   = (const float*)d_in[22];
    const float* l2b   = (const float*)d_in[23];
    const float* n3g   = (const float*)d_in[24];
    const float* n3b   = (const float*)d_in[25];
    float* out = (float*)d_out;

    char* p = (char*)d_ws;
    auto alloc = [&](size_t bytes) {
        char* r = p; p += (bytes + 255) & ~(size_t)255; return (void*)r;
    };
    unsigned short* wtIn   = (unsigned short*)alloc(768 * 256 * 2);
    unsigned short* wtOut  = (unsigned short*)alloc(256 * 256 * 2);
    unsigned short* wtVp   = (unsigned short*)alloc(256 * 256 * 2);
    unsigned short* wtOp   = (unsigned short*)alloc(256 * 256 * 2);
    unsigned short* wtL1   = (unsigned short*)alloc(2048 * 256 * 2);
    unsigned short* wtL2   = (unsigned short*)alloc(256 * 2048 * 2);
    unsigned short* wtHead = (unsigned short*)alloc(128 * 256 * 2);
    float*          headb  = (float*)alloc(128 * 4);
    float* qkv  = (float*)alloc((size_t)NROW * 768 * 4);
    float* sa   = (float*)alloc((size_t)NROW * ND * 4);
    float* x1   = (float*)alloc((size_t)NROW * ND * 4);
    float* x2   = (float*)alloc((size_t)NROW * ND * 4);
    float* tmp  = (float*)alloc((size_t)NROW * ND * 4);
    float* ca   = (float*)alloc((size_t)NROW * ND * 4);
    float* meta = (float*)alloc((size_t)NROW * 256 * 4);
    void* uni = alloc((size_t)NB * NHW * ND * 2);   // vals bf16 / h1 fp32 alias
    unsigned short* vals = (unsigned short*)uni;
    float* h1 = (float*)uni;
    float* res = qkv;   // head-GEMM result [4800][128]; qkv is dead by then

    prep_weights<<<5761, 256, 0, stream>>>(
        inpw, outw, vpw, opw, l1w, l2w,
        refw, refb, offw, offb, attww, attwb,
        wtIn, wtOut, wtVp, wtOp, wtL1, wtL2, wtHead, headb);

    gemm_bt<0, 0, 2><<<dim3(3, 38), 256, 0, stream>>>(tgt, wtIn, inpb, qkv,
                                                      NROW, 768, 256);
    gemm_bt<0, 1, 2><<<dim3(1, 1250), 256, 0, stream>>>(mem, wtVp, vpb, vals,
                                                        NB * NHW, 256, 256);
    attn_kernel<<<dim3(5, 128), 256, 0, stream>>>(qkv, sa);
    gemm_bt<0, 0, 2><<<dim3(1, 38), 256, 0, stream>>>(sa, wtOut, outb, tmp,
                                                      NROW, 256, 256);
    residual_ln<<<1200, 256, 0, stream>>>(tgt, tmp, n1g, n1b, x1);
    gemm_bt<0, 0, 1><<<dim3(1, 38), 256, 0, stream>>>(x1, wtHead, headb, res,
                                                      NROW, 128, 256);
    meta_kernel<<<600, 256, 0, stream>>>(res, meta);
    deform_gather<<<4800, 256, 0, stream>>>(meta, vals, ca);
    gemm_bt<0, 0, 2><<<dim3(1, 38), 256, 0, stream>>>(ca, wtOp, opb, tmp,
                                                      NROW, 256, 256);
    residual_ln<<<1200, 256, 0, stream>>>(x1, tmp, n2g, n2b, x2);
    gemm_bt<1, 0, 2><<<dim3(8, 38), 256, 0, stream>>>(x2, wtL1, l1b, h1,
                                                      NROW, 2048, 256);
    gemm_bt<0, 0, 2><<<dim3(1, 38), 256, 0, stream>>>(h1, wtL2, l2b, tmp,
                                                      NROW, 256, 2048);
    residual_ln<<<1200, 256, 0, stream>>>(x2, tmp, n3g, n3b, out);
}

// Round 3
// 578.154 us; speedup vs baseline: 1.2870x; 1.1794x over previous
//
#include <hip/hip_runtime.h>

// Problem constants
#define NB   16
#define NQ   300
#define ND   256
#define NH   8
#define NP   4
#define NF   2048
#define NHW  10000
#define NWG  100
#define NROW 4800          // NB*NQ

typedef __attribute__((ext_vector_type(8))) short bf16x8;
typedef __attribute__((ext_vector_type(4))) float f32x4;

__device__ __forceinline__ unsigned short f2bf(float f) {
    unsigned u = __builtin_bit_cast(unsigned, f);
    u = (u + 0x7fffu + ((u >> 16) & 1u)) >> 16;   // RNE
    return (unsigned short)u;
}
__device__ __forceinline__ float bf2f(unsigned short h) {
    unsigned u = ((unsigned)h) << 16;
    return __builtin_bit_cast(float, u);
}

// ---------------------------------------------------------------------------
// Weight prep: transpose fp32 [K][N] -> bf16 [N][K] for GEMM weights, plus
// the concatenated head weight [128][256] (ref 2 | off 64 | attw 32 | pad 30)
// and its fp32 bias[128].
// ---------------------------------------------------------------------------
__global__ __launch_bounds__(256) void prep_weights(
    const float* __restrict__ w_in,  const float* __restrict__ w_out,
    const float* __restrict__ w_vp,  const float* __restrict__ w_op,
    const float* __restrict__ w_l1,  const float* __restrict__ w_l2,
    const float* __restrict__ rw, const float* __restrict__ rb,
    const float* __restrict__ ow, const float* __restrict__ ob,
    const float* __restrict__ aw, const float* __restrict__ ab,
    unsigned short* __restrict__ o_in, unsigned short* __restrict__ o_out,
    unsigned short* __restrict__ o_vp, unsigned short* __restrict__ o_op,
    unsigned short* __restrict__ o_l1, unsigned short* __restrict__ o_l2,
    unsigned short* __restrict__ o_hd, float* __restrict__ o_hb)
{
    int id = blockIdx.x * 256 + threadIdx.x;
    if (id < 196608) {                       // in_proj: [256][768] -> [768][256]
        int n = id >> 8, k = id & 255;
        o_in[id] = f2bf(w_in[k * 768 + n]);  return;
    }
    id -= 196608;
    if (id < 65536) {                        // out_proj
        int n = id >> 8, k = id & 255;
        o_out[id] = f2bf(w_out[k * 256 + n]); return;
    }
    id -= 65536;
    if (id < 65536) {                        // vproj
        int n = id >> 8, k = id & 255;
        o_vp[id] = f2bf(w_vp[k * 256 + n]);  return;
    }
    id -= 65536;
    if (id < 65536) {                        // oproj
        int n = id >> 8, k = id & 255;
        o_op[id] = f2bf(w_op[k * 256 + n]);  return;
    }
    id -= 65536;
    if (id < 524288) {                       // lin1: [256][2048] -> [2048][256]
        int n = id >> 8, k = id & 255;
        o_l1[id] = f2bf(w_l1[k * 2048 + n]); return;
    }
    id -= 524288;
    if (id < 524288) {                       // lin2: [2048][256] -> [256][2048]
        int n = id >> 11, k = id & 2047;
        o_l2[id] = f2bf(w_l2[k * 256 + n]);  return;
    }
    id -= 524288;
    if (id < 32768) {                        // head concat weight [128][256]
        int n = id >> 8, k = id & 255;
        float v;
        if (n < 2)       v = rw[k * 2 + n];
        else if (n < 66) v = ow[k * 64 + (n - 2)];
        else if (n < 98) v = aw[k * 32 + (n - 66)];
        else             v = 0.0f;
        o_hd[id] = f2bf(v);                  return;
    }
    id -= 32768;
    if (id < 128) {                          // head bias
        float v;
        if (id < 2)       v = rb[id];
        else if (id < 66) v = ob[id - 2];
        else if (id < 98) v = ab[id - 66];
        else              v = 0.0f;
        o_hb[id] = v;
    }
}

// ---------------------------------------------------------------------------
// bf16 MFMA GEMM: C[M,N] = A[M,K](fp32) * Bt[N,K](bf16)^T + bias, opt ReLU,
// fp32 or bf16 output. Tile 128 x (128*NT), BK=32, 256 threads (4 waves).
// Epilogue: C-tile round-trips LDS (4 passes of 32 x NC fp32) -> coalesced
// dwordx4 stores (16-32 per thread instead of 128 scalar stores).
// SPLITK>1: each z-block handles K/SPLITK; fp32 atomicAdd epilogue (bias on
// z==0 only; output must be pre-zeroed; no ReLU).
// ---------------------------------------------------------------------------
template <int RELU, int OUTBF, int NT, int SPLITK>
__global__ __launch_bounds__(256, 2) void gemm_bt(
    const float* __restrict__ A, const unsigned short* __restrict__ Bt,
    const float* __restrict__ bias, void* __restrict__ Cout,
    int M, int N, int K)
{
    constexpr int NC = 128 * NT;
    __shared__ union {
        struct {
            unsigned short As[128][40];
            unsigned short Bs[128 * NT][40];
        } st;
        float C[32][NC + 4];
    } u;
    const int t    = threadIdx.x;
    const long m0  = (long)blockIdx.y * 128;
    const int  n0  = blockIdx.x * NC;
    const int  sr  = t >> 1;            // staging row 0..127
    const int  sc  = (t & 1) << 4;      // staging col 0 or 16
    const int  wave = t >> 6, lane = t & 63;
    const int  wm  = (wave >> 1) << 6;
    const int  wn  = (wave & 1) * (64 * NT);
    const int  l16 = lane & 15, quad = lane >> 4;

    f32x4 acc[4][4 * NT] = {};

    const bool aOk = (m0 + sr) < M;
    const float* aBase = A + (m0 + sr) * (long)K + sc;

    const int kChunk = K / SPLITK;
    const int kBeg   = (SPLITK > 1) ? blockIdx.z * kChunk : 0;

    for (int k0 = kBeg; k0 < kBeg + kChunk; k0 += 32) {
        unsigned short ta[16];
        if (aOk) {
            const float4* ap = (const float4*)(aBase + k0);
            #pragma unroll
            for (int i = 0; i < 4; i++) {
                float4 f = ap[i];
                ta[i * 4 + 0] = f2bf(f.x); ta[i * 4 + 1] = f2bf(f.y);
                ta[i * 4 + 2] = f2bf(f.z); ta[i * 4 + 3] = f2bf(f.w);
            }
        } else {
            #pragma unroll
            for (int i = 0; i < 16; i++) ta[i] = 0;
        }
        *(bf16x8*)&u.st.As[sr][sc]     = *(bf16x8*)&ta[0];
        *(bf16x8*)&u.st.As[sr][sc + 8] = *(bf16x8*)&ta[8];
        #pragma unroll
        for (int rep = 0; rep < NT; rep++) {
            const int row = sr + rep * 128;
            uint4 tb0, tb1;
            if (n0 + row < N) {
                const uint4* bp = (const uint4*)(Bt + (long)(n0 + row) * K + sc + k0);
                tb0 = bp[0]; tb1 = bp[1];
            } else {
                tb0 = make_uint4(0, 0, 0, 0); tb1 = tb0;
            }
            *(uint4*)&u.st.Bs[row][sc]     = tb0;
            *(uint4*)&u.st.Bs[row][sc + 8] = tb1;
        }
        __syncthreads();

        bf16x8 af[4], bfr[4 * NT];
        #pragma unroll
        for (int i = 0; i < 4; i++)
            af[i] = *(const bf16x8*)&u.st.As[wm + i * 16 + l16][quad * 8];
        #pragma unroll
        for (int j = 0; j < 4 * NT; j++)
            bfr[j] = *(const bf16x8*)&u.st.Bs[wn + j * 16 + l16][quad * 8];
        #pragma unroll
        for (int i = 0; i < 4; i++)
            #pragma unroll
            for (int j = 0; j < 4 * NT; j++)
                acc[i][j] = __builtin_amdgcn_mfma_f32_16x16x32_bf16(
                    af[i], bfr[j], acc[i][j], 0, 0, 0);
        __syncthreads();
    }

    float bv[4 * NT];
    #pragma unroll
    for (int j = 0; j < 4 * NT; j++) bv[j] = bias[n0 + wn + j * 16 + l16];

    if (SPLITK > 1) {
        const float bscale = (blockIdx.z == 0) ? 1.0f : 0.0f;
        #pragma unroll
        for (int i = 0; i < 4; i++)
            #pragma unroll
            for (int j = 0; j < 4 * NT; j++)
                #pragma unroll
                for (int r = 0; r < 4; r++) {
                    long gr = m0 + wm + i * 16 + quad * 4 + r;
                    if (gr < M)
                        atomicAdd((float*)Cout + gr * N + n0 + wn + j * 16 + l16,
                                  acc[i][j][r] + bscale * bv[j]);
                }
        return;
    }

    // LDS-staged epilogue: pass i covers tile rows [i*16,i*16+16) u [64+i*16,..)
    const int lr = t >> 3;                   // lds row 0..31
    const int cb = (t & 7) * (NC / 8);       // col base
    #pragma unroll
    for (int i = 0; i < 4; i++) {
        #pragma unroll
        for (int j = 0; j < 4 * NT; j++)
            #pragma unroll
            for (int r = 0; r < 4; r++) {
                float v = acc[i][j][r] + bv[j];
                if (RELU) v = fmaxf(v, 0.0f);
                u.C[(wave >> 1) * 16 + quad * 4 + r][wn + j * 16 + l16] = v;
            }
        __syncthreads();
        const long gr = m0 + (lr >> 4) * 64 + i * 16 + (lr & 15);
        if (gr < M) {
            if (OUTBF) {
                unsigned short* op = (unsigned short*)Cout + gr * N + n0 + cb;
                #pragma unroll
                for (int c = 0; c < NC / 8; c += 8) {
                    float4 f0 = *(float4*)&u.C[lr][cb + c];
                    float4 f1 = *(float4*)&u.C[lr][cb + c + 4];
                    uint4 o;
                    o.x = f2bf(f0.x) | ((unsigned)f2bf(f0.y) << 16);
                    o.y = f2bf(f0.z) | ((unsigned)f2bf(f0.w) << 16);
                    o.z = f2bf(f1.x) | ((unsigned)f2bf(f1.y) << 16);
                    o.w = f2bf(f1.z) | ((unsigned)f2bf(f1.w) << 16);
                    *(uint4*)(op + c) = o;
                }
            } else {
                float* op = (float*)Cout + gr * N + n0 + cb;
                #pragma unroll
                for (int c = 0; c < NC / 8; c += 4)
                    *(float4*)(op + c) = *(float4*)&u.C[lr][cb + c];
            }
        }
        __syncthreads();
    }
}

// ---------------------------------------------------------------------------
// MFMA self-attention. Grid (5 q-tiles, 128 b*h). Block = 256 thr = 4 waves;
// wave w owns q-rows [q0+16w, q0+16w+16).
// ---------------------------------------------------------------------------
__global__ __launch_bounds__(256) void attn_kernel(
    const float* __restrict__ qkv, float* __restrict__ sa)
{
    __shared__ union {
        struct {
            unsigned short Ks[304][40];   // 24,320 B
            unsigned short Qs[64][40];    //  5,120 B
        } s;
        unsigned short Ps[4][16][328];    // 41,984 B
    } u;
    __shared__ unsigned short Vt[32][328]; // 20,992 B  (total 62,976 B)

    const int bh = blockIdx.y;            // b*8 + h
    const int b  = bh >> 3, h = bh & 7;
    const int q0 = blockIdx.x * 64;
    const int t  = threadIdx.x;

    for (int idx = t; idx < 304 * 8; idx += 256) {
        const int r = idx >> 3, c4 = (idx & 7) << 2;
        if (r < NQ) {
            const float4 kv = *(const float4*)(qkv + ((long)(b * NQ + r)) * 768 + 256 + h * 32 + c4);
            u.s.Ks[r][c4 + 0] = f2bf(kv.x); u.s.Ks[r][c4 + 1] = f2bf(kv.y);
            u.s.Ks[r][c4 + 2] = f2bf(kv.z); u.s.Ks[r][c4 + 3] = f2bf(kv.w);
        } else {
            u.s.Ks[r][c4 + 0] = 0; u.s.Ks[r][c4 + 1] = 0;
            u.s.Ks[r][c4 + 2] = 0; u.s.Ks[r][c4 + 3] = 0;
        }
    }
    for (int idx = t; idx < NQ * 8; idx += 256) {
        const int key = idx >> 3, dq = (idx & 7) << 2;
        const float4 vv = *(const float4*)(qkv + ((long)(b * NQ + key)) * 768 + 512 + h * 32 + dq);
        Vt[dq + 0][key] = f2bf(vv.x); Vt[dq + 1][key] = f2bf(vv.y);
        Vt[dq + 2][key] = f2bf(vv.z); Vt[dq + 3][key] = f2bf(vv.w);
    }
    for (int idx = t; idx < 32 * 20; idx += 256)   // zero keys 300..319
        Vt[idx / 20][300 + idx % 20] = 0;
    for (int idx = t; idx < 64 * 8; idx += 256) {
        const int r = idx >> 3, c4 = (idx & 7) << 2;
        const int q = q0 + r;
        if (q < NQ) {
            const float4 qv = *(const float4*)(qkv + ((long)(b * NQ + q)) * 768 + h * 32 + c4);
            u.s.Qs[r][c4 + 0] = f2bf(qv.x); u.s.Qs[r][c4 + 1] = f2bf(qv.y);
            u.s.Qs[r][c4 + 2] = f2bf(qv.z); u.s.Qs[r][c4 + 3] = f2bf(qv.w);
        } else {
            u.s.Qs[r][c4 + 0] = 0; u.s.Qs[r][c4 + 1] = 0;
            u.s.Qs[r][c4 + 2] = 0; u.s.Qs[r][c4 + 3] = 0;
        }
    }
    __syncthreads();

    const int wave = t >> 6, lane = t & 63;
    const int l16 = lane & 15, quad = lane >> 4;
    const float scale = 0.1767766952966369f;   // 1/sqrt(32)

    const bf16x8 aq = *(const bf16x8*)&u.s.Qs[wave * 16 + l16][quad * 8];
    f32x4 sacc[19];
    #pragma unroll
    for (int kt = 0; kt < 19; kt++) {
        const bf16x8 bk = *(const bf16x8*)&u.s.Ks[kt * 16 + l16][quad * 8];
        sacc[kt] = __builtin_amdgcn_mfma_f32_16x16x32_bf16(
            aq, bk, (f32x4){0.f, 0.f, 0.f, 0.f}, 0, 0, 0);
    }

    float inv[4];
    #pragma unroll
    for (int r = 0; r < 4; r++) {
        float m = -1e30f;
        #pragma unroll
        for (int kt = 0; kt < 19; kt++) {
            float s = sacc[kt][r] * scale;
            if (kt == 18 && l16 >= 12) s = -1e30f;    // keys 300..303 invalid
            sacc[kt][r] = s;
            m = fmaxf(m, s);
        }
        m = fmaxf(m, __shfl_xor(m, 1)); m = fmaxf(m, __shfl_xor(m, 2));
        m = fmaxf(m, __shfl_xor(m, 4)); m = fmaxf(m, __shfl_xor(m, 8));
        float sum = 0.f;
        #pragma unroll
        for (int kt = 0; kt < 19; kt++) {
            float p = __expf(sacc[kt][r] - m);
            sacc[kt][r] = p;
            sum += p;
        }
        sum += __shfl_xor(sum, 1); sum += __shfl_xor(sum, 2);
        sum += __shfl_xor(sum, 4); sum += __shfl_xor(sum, 8);
        inv[r] = 1.0f / sum;
    }

    __syncthreads();   // all waves done with Ks/Qs before Ps overwrites them

    #pragma unroll
    for (int kt = 0; kt < 19; kt++)
        #pragma unroll
        for (int r = 0; r < 4; r++)
            u.Ps[wave][quad * 4 + r][kt * 16 + l16] = f2bf(sacc[kt][r] * inv[r]);
    #pragma unroll
    for (int r = 0; r < 4; r++)      // zero pad keys 304..319
        u.Ps[wave][quad * 4 + r][304 + l16] = 0;

    f32x4 o0 = {0.f, 0.f, 0.f, 0.f}, o1 = {0.f, 0.f, 0.f, 0.f};
    #pragma unroll
    for (int kt = 0; kt < 10; kt++) {
        const bf16x8 ap  = *(const bf16x8*)&u.Ps[wave][l16][kt * 32 + quad * 8];
        const bf16x8 bv0 = *(const bf16x8*)&Vt[l16][kt * 32 + quad * 8];
        const bf16x8 bv1 = *(const bf16x8*)&Vt[16 + l16][kt * 32 + quad * 8];
        o0 = __builtin_amdgcn_mfma_f32_16x16x32_bf16(ap, bv0, o0, 0, 0, 0);
        o1 = __builtin_amdgcn_mfma_f32_16x16x32_bf16(ap, bv1, o1, 0, 0, 0);
    }

    #pragma unroll
    for (int r = 0; r < 4; r++) {
        const int q = q0 + wave * 16 + quad * 4 + r;
        if (q < NQ) {
            float* op = sa + ((long)(b * NQ + q)) * ND + h * 32;
            op[l16]      = o0[r];
            op[16 + l16] = o1[r];
        }
    }
}

// ---------------------------------------------------------------------------
// Residual + LayerNorm: one wave per row of 256.
// ---------------------------------------------------------------------------
__global__ __launch_bounds__(256) void residual_ln(
    const float* __restrict__ a, const float* __restrict__ r,
    const float* __restrict__ gam, const float* __restrict__ bet,
    float* __restrict__ out)
{
    const int row  = blockIdx.x * 4 + (threadIdx.x >> 6);
    const int lane = threadIdx.x & 63;
    const long base = (long)row * ND + lane * 4;
    float4 av = *(const float4*)(a + base);
    float4 rv = *(const float4*)(r + base);
    float x0 = av.x + rv.x, x1 = av.y + rv.y, x2 = av.z + rv.z, x3 = av.w + rv.w;
    float s  = x0 + x1 + x2 + x3;
    float s2 = x0 * x0 + x1 * x1 + x2 * x2 + x3 * x3;
    #pragma unroll
    for (int off = 32; off >= 1; off >>= 1) {
        s  += __shfl_xor(s, off);
        s2 += __shfl_xor(s2, off);
    }
    float mean = s * 0.00390625f;
    float var  = s2 * 0.00390625f - mean * mean;
    float rstd = rsqrtf(var + 1e-5f);
    float4 gv = *(const float4*)(gam + lane * 4);
    float4 bv = *(const float4*)(bet + lane * 4);
    float4 o;
    o.x = (x0 - mean) * rstd * gv.x + bv.x;
    o.y = (x1 - mean) * rstd * gv.y + bv.y;
    o.z = (x2 - mean) * rstd * gv.z + bv.z;
    o.w = (x3 - mean) * rstd * gv.w + bv.w;
    *(float4*)(out + base) = o;
}

// ---------------------------------------------------------------------------
// meta from head-GEMM result res[4800][128].
// ---------------------------------------------------------------------------
__global__ __launch_bounds__(256) void meta_kernel(
    const float* __restrict__ res, float* __restrict__ meta)
{
    const int t   = threadIdx.x;
    const int row = blockIdx.x * 8 + (t >> 5);
    const int s   = t & 31;
    const int h   = s >> 2;
    const float* rp = res + (long)row * 128;
    const float rx = 1.f / (1.f + __expf(-rp[0]));
    const float ry = 1.f / (1.f + __expf(-rp[1]));
    const float offx = rp[2 + 2 * s], offy = rp[3 + 2 * s];
    const float a0 = rp[66 + h * 4 + 0], a1 = rp[66 + h * 4 + 1];
    const float a2 = rp[66 + h * 4 + 2], a3 = rp[66 + h * 4 + 3];
    const float mx = fmaxf(fmaxf(a0, a1), fmaxf(a2, a3));
    const float den = __expf(a0 - mx) + __expf(a1 - mx) +
                      __expf(a2 - mx) + __expf(a3 - mx);
    const float awt = __expf(rp[66 + s] - mx) / den;

    const float lx = fminf(fmaxf(rx + offx, 0.f), 1.f) * (NWG - 1);
    const float ly = fminf(fmaxf(ry + offy, 0.f), 1.f) * (NWG - 1);
    const float fx = floorf(lx), fy = floorf(ly);
    int x0 = (int)fx; x0 = min(max(x0, 0), NWG - 1);
    int y0 = (int)fy; y0 = min(max(y0, 0), NWG - 1);
    const int x1 = min(x0 + 1, NWG - 1);
    const int y1 = min(y0 + 1, NWG - 1);
    const float wx1 = lx - fx, wx0 = 1.f - wx1;
    const float wy1 = ly - fy, wy0 = 1.f - wy1;
    float4 m0, m1;
    m0.x = __int_as_float(y0 * NWG + x0);
    m0.y = __int_as_float(y0 * NWG + x1);
    m0.z = __int_as_float(y1 * NWG + x0);
    m0.w = __int_as_float(y1 * NWG + x1);
    m1.x = awt * wx0 * wy0;
    m1.y = awt * wx1 * wy0;
    m1.z = awt * wx0 * wy1;
    m1.w = awt * wx1 * wy1;
    float* mp = meta + (long)row * 256 + s * 8;
    *(float4*)mp       = m0;
    *(float4*)(mp + 4) = m1;
}

// ---------------------------------------------------------------------------
// Deformable gather: block per (b,q); thread (h = t>>5, d = t&31).
// ---------------------------------------------------------------------------
__global__ __launch_bounds__(256) void deform_gather(
    const float* __restrict__ meta, const unsigned short* __restrict__ vals,
    float* __restrict__ ca)
{
    const int row = blockIdx.x;           // b*300+q
    const int b = row / NQ;
    __shared__ float ms[256];
    const int t = threadIdx.x;
    ms[t] = meta[(long)row * 256 + t];
    __syncthreads();
    const int h = t >> 5, d = t & 31;
    const unsigned short* vb = vals + (long)b * NHW * ND + h * 32 + d;
    float acc = 0.f;
    #pragma unroll
    for (int p = 0; p < NP; p++) {
        const float* mp = ms + h * 32 + p * 8;
        const int i00 = __float_as_int(mp[0]);
        const int i01 = __float_as_int(mp[1]);
        const int i10 = __float_as_int(mp[2]);
        const int i11 = __float_as_int(mp[3]);
        acc += mp[4] * bf2f(vb[(long)i00 * ND]);
        acc += mp[5] * bf2f(vb[(long)i01 * ND]);
        acc += mp[6] * bf2f(vb[(long)i10 * ND]);
        acc += mp[7] * bf2f(vb[(long)i11 * ND]);
    }
    ca[(long)row * ND + t] = acc;
}

// ---------------------------------------------------------------------------
extern "C" void kernel_launch(void* const* d_in, const int* in_sizes, int n_in,
                              void* d_out, int out_size, void* d_ws, size_t ws_size,
                              hipStream_t stream)
{
    (void)in_sizes; (void)n_in; (void)out_size; (void)ws_size;
    const float* tgt   = (const float*)d_in[0];
    const float* mem   = (const float*)d_in[1];
    const float* inpw  = (const float*)d_in[2];
    const float* inpb  = (const float*)d_in[3];
    const float* outw  = (const float*)d_in[4];
    const float* outb  = (const float*)d_in[5];
    const float* n1g   = (const float*)d_in[6];
    const float* n1b   = (const float*)d_in[7];
    const float* refw  = (const float*)d_in[8];
    const float* refb  = (const float*)d_in[9];
    const float* offw  = (const float*)d_in[10];
    const float* offb  = (const float*)d_in[11];
    const float* attww = (const float*)d_in[12];
    const float* attwb = (const float*)d_in[13];
    const float* vpw   = (const float*)d_in[14];
    const float* vpb   = (const float*)d_in[15];
    const float* opw   = (const float*)d_in[16];
    const float* opb   = (const float*)d_in[17];
    const float* n2g   = (const float*)d_in[18];
    const float* n2b   = (const float*)d_in[19];
    const float* l1w   = (const float*)d_in[20];
    const float* l1b   = (const float*)d_in[21];
    const float* l2w   = (const float*)d_in[22];
    const float* l2b   = (const float*)d_in[23];
    const float* n3g   = (const float*)d_in[24];
    const float* n3b   = (const float*)d_in[25];
    float* out = (float*)d_out;

    char* p = (char*)d_ws;
    auto alloc = [&](size_t bytes) {
        char* r = p; p += (bytes + 255) & ~(size_t)255; return (void*)r;
    };
    unsigned short* wtIn   = (unsigned short*)alloc(768 * 256 * 2);
    unsigned short* wtOut  = (unsigned short*)alloc(256 * 256 * 2);
    unsigned short* wtVp   = (unsigned short*)alloc(256 * 256 * 2);
    unsigned short* wtOp   = (unsigned short*)alloc(256 * 256 * 2);
    unsigned short* wtL1   = (unsigned short*)alloc(2048 * 256 * 2);
    unsigned short* wtL2   = (unsigned short*)alloc(256 * 2048 * 2);
    unsigned short* wtHead = (unsigned short*)alloc(128 * 256 * 2);
    float*          headb  = (float*)alloc(128 * 4);
    float* qkv  = (float*)alloc((size_t)NROW * 768 * 4);
    float* sa   = (float*)alloc((size_t)NROW * ND * 4);
    float* x1   = (float*)alloc((size_t)NROW * ND * 4);
    float* x2   = (float*)alloc((size_t)NROW * ND * 4);
    float* tmp  = (float*)alloc((size_t)NROW * ND * 4);
    float* ca   = (float*)alloc((size_t)NROW * ND * 4);
    float* meta = (float*)alloc((size_t)NROW * 256 * 4);
    void* uni = alloc((size_t)NB * NHW * ND * 2);   // vals bf16 / h1 fp32 alias
    unsigned short* vals = (unsigned short*)uni;
    float* h1 = (float*)uni;
    float* res = qkv;   // head-GEMM result [4800][128]; qkv is dead by then

    prep_weights<<<5761, 256, 0, stream>>>(
        inpw, outw, vpw, opw, l1w, l2w,
        refw, refb, offw, offb, attww, attwb,
        wtIn, wtOut, wtVp, wtOp, wtL1, wtL2, wtHead, headb);

    gemm_bt<0, 0, 2, 1><<<dim3(3, 38), 256, 0, stream>>>(tgt, wtIn, inpb, qkv,
                                                         NROW, 768, 256);
    gemm_bt<0, 1, 2, 1><<<dim3(1, 1250), 256, 0, stream>>>(mem, wtVp, vpb, vals,
                                                           NB * NHW, 256, 256);
    attn_kernel<<<dim3(5, 128), 256, 0, stream>>>(qkv, sa);
    gemm_bt<0, 0, 2, 1><<<dim3(1, 38), 256, 0, stream>>>(sa, wtOut, outb, tmp,
                                                         NROW, 256, 256);
    residual_ln<<<1200, 256, 0, stream>>>(tgt, tmp, n1g, n1b, x1);
    gemm_bt<0, 0, 1, 1><<<dim3(1, 38), 256, 0, stream>>>(x1, wtHead, headb, res,
                                                         NROW, 128, 256);
    meta_kernel<<<600, 256, 0, stream>>>(res, meta);
    deform_gather<<<4800, 256, 0, stream>>>(meta, vals, ca);
    gemm_bt<0, 0, 2, 1><<<dim3(1, 38), 256, 0, stream>>>(ca, wtOp, opb, tmp,
                                                         NROW, 256, 256);
    residual_ln<<<1200, 256, 0, stream>>>(x1, tmp, n2g, n2b, x2);
    gemm_bt<1, 0, 2, 1><<<dim3(8, 38), 256, 0, stream>>>(x2, wtL1, l1b, h1,
                                                         NROW, 2048, 256);
    hipMemsetAsync(tmp, 0, (size_t)NROW * ND * 4, stream);
    gemm_bt<0, 0, 2, 4><<<dim3(1, 38, 4), 256, 0, stream>>>(h1, wtL2, l2b, tmp,
                                                            NROW, 256, 2048);
    residual_ln<<<1200, 256, 0, stream>>>(x2, tmp, n3g, n3b, out);
}

// Round 4
// 544.448 us; speedup vs baseline: 1.3667x; 1.0619x over previous
//
#include <hip/hip_runtime.h>

// Problem constants
#define NB   16
#define NQ   300
#define ND   256
#define NH   8
#define NP   4
#define NF   2048
#define NHW  10000
#define NWG  100
#define NROW 4800          // NB*NQ

typedef __attribute__((ext_vector_type(8))) short bf16x8;
typedef __attribute__((ext_vector_type(4))) float f32x4;

__device__ __forceinline__ unsigned short f2bf(float f) {
    unsigned u = __builtin_bit_cast(unsigned, f);
    u = (u + 0x7fffu + ((u >> 16) & 1u)) >> 16;   // RNE
    return (unsigned short)u;
}
__device__ __forceinline__ float bf2f(unsigned short h) {
    unsigned u = ((unsigned)h) << 16;
    return __builtin_bit_cast(float, u);
}

// ---------------------------------------------------------------------------
// Weight prep: transpose fp32 [K][N] -> bf16 [N][K] for GEMM weights, plus
// the concatenated head weight [128][256] (ref 2 | off 64 | attw 32 | pad 30)
// and its fp32 bias[128].
// ---------------------------------------------------------------------------
__global__ __launch_bounds__(256) void prep_weights(
    const float* __restrict__ w_in,  const float* __restrict__ w_out,
    const float* __restrict__ w_vp,  const float* __restrict__ w_op,
    const float* __restrict__ w_l1,  const float* __restrict__ w_l2,
    const float* __restrict__ rw, const float* __restrict__ rb,
    const float* __restrict__ ow, const float* __restrict__ ob,
    const float* __restrict__ aw, const float* __restrict__ ab,
    unsigned short* __restrict__ o_in, unsigned short* __restrict__ o_out,
    unsigned short* __restrict__ o_vp, unsigned short* __restrict__ o_op,
    unsigned short* __restrict__ o_l1, unsigned short* __restrict__ o_l2,
    unsigned short* __restrict__ o_hd, float* __restrict__ o_hb)
{
    int id = blockIdx.x * 256 + threadIdx.x;
    if (id < 196608) {                       // in_proj: [256][768] -> [768][256]
        int n = id >> 8, k = id & 255;
        o_in[id] = f2bf(w_in[k * 768 + n]);  return;
    }
    id -= 196608;
    if (id < 65536) {                        // out_proj
        int n = id >> 8, k = id & 255;
        o_out[id] = f2bf(w_out[k * 256 + n]); return;
    }
    id -= 65536;
    if (id < 65536) {                        // vproj
        int n = id >> 8, k = id & 255;
        o_vp[id] = f2bf(w_vp[k * 256 + n]);  return;
    }
    id -= 65536;
    if (id < 65536) {                        // oproj
        int n = id >> 8, k = id & 255;
        o_op[id] = f2bf(w_op[k * 256 + n]);  return;
    }
    id -= 65536;
    if (id < 524288) {                       // lin1: [256][2048] -> [2048][256]
        int n = id >> 8, k = id & 255;
        o_l1[id] = f2bf(w_l1[k * 2048 + n]); return;
    }
    id -= 524288;
    if (id < 524288) {                       // lin2: [2048][256] -> [256][2048]
        int n = id >> 11, k = id & 2047;
        o_l2[id] = f2bf(w_l2[k * 256 + n]);  return;
    }
    id -= 524288;
    if (id < 32768) {                        // head concat weight [128][256]
        int n = id >> 8, k = id & 255;
        float v;
        if (n < 2)       v = rw[k * 2 + n];
        else if (n < 66) v = ow[k * 64 + (n - 2)];
        else if (n < 98) v = aw[k * 32 + (n - 66)];
        else             v = 0.0f;
        o_hd[id] = f2bf(v);                  return;
    }
    id -= 32768;
    if (id < 128) {                          // head bias
        float v;
        if (id < 2)       v = rb[id];
        else if (id < 66) v = ob[id - 2];
        else if (id < 98) v = ab[id - 66];
        else              v = 0.0f;
        o_hb[id] = v;
    }
}

// ---------------------------------------------------------------------------
// bf16 MFMA GEMM: C[M,N] = A[M,K](fp32) * Bt[N,K](bf16)^T + bias, opt ReLU,
// fp32 or bf16 output. Tile 128x128, BK=32, 256 threads (4 waves, 64x64).
// Double-buffered LDS, ONE barrier per K-iter; global loads for iter k+1
// issue before the MFMA of iter k (raw fp32/uint regs; cvt at LDS-write).
// MFMA operands SWAPPED -> thread holds C row m=l16, cols n=quad*4+r:
// register-direct coalesced float4 epilogue, no LDS round trip.
// SPLITK>1: z-blocks over K, fp32 atomicAdd epilogue (bias z==0 only;
// output pre-zeroed; no ReLU).
// ---------------------------------------------------------------------------
template <int RELU, int OUTBF, int SPLITK>
__global__ __launch_bounds__(256, 3) void gemm_bt(
    const float* __restrict__ A, const unsigned short* __restrict__ Bt,
    const float* __restrict__ bias, void* __restrict__ Cout,
    int M, int N, int K)
{
    __shared__ unsigned short As[2][128][40];
    __shared__ unsigned short Bs[2][128][40];
    const int t    = threadIdx.x;
    const long m0  = (long)blockIdx.y * 128;
    const int  n0  = blockIdx.x * 128;
    const int  sr  = t >> 1;            // staging row 0..127
    const int  sc  = (t & 1) << 4;      // staging col 0 or 16
    const int  wave = t >> 6, lane = t & 63;
    const int  wm  = (wave >> 1) << 6;
    const int  wn  = (wave & 1) << 6;
    const int  l16 = lane & 15, quad = lane >> 4;

    f32x4 acc[4][4] = {};

    const bool aOk = (m0 + sr) < M;
    const float* aBase          = A  + (m0 + sr) * (long)K + sc;
    const unsigned short* bBase = Bt + (long)(n0 + sr) * K + sc;  // N % 128 == 0

    const int kChunk = K / SPLITK;
    const int kBeg   = (SPLITK > 1) ? blockIdx.z * kChunk : 0;
    const int nk     = kChunk / 32;

    float4 fa0, fa1, fa2, fa3;
    uint4  tb0, tb1;

    auto loadAB = [&](int kt) {
        const int k0 = kBeg + kt * 32;
        if (aOk) {
            const float4* ap = (const float4*)(aBase + k0);
            fa0 = ap[0]; fa1 = ap[1]; fa2 = ap[2]; fa3 = ap[3];
        } else {
            fa0 = make_float4(0, 0, 0, 0); fa1 = fa0; fa2 = fa0; fa3 = fa0;
        }
        const uint4* bp = (const uint4*)(bBase + k0);
        tb0 = bp[0]; tb1 = bp[1];
    };
    auto storeLDS = [&](int buf) {
        unsigned short ta[16];
        ta[0]  = f2bf(fa0.x); ta[1]  = f2bf(fa0.y); ta[2]  = f2bf(fa0.z); ta[3]  = f2bf(fa0.w);
        ta[4]  = f2bf(fa1.x); ta[5]  = f2bf(fa1.y); ta[6]  = f2bf(fa1.z); ta[7]  = f2bf(fa1.w);
        ta[8]  = f2bf(fa2.x); ta[9]  = f2bf(fa2.y); ta[10] = f2bf(fa2.z); ta[11] = f2bf(fa2.w);
        ta[12] = f2bf(fa3.x); ta[13] = f2bf(fa3.y); ta[14] = f2bf(fa3.z); ta[15] = f2bf(fa3.w);
        *(bf16x8*)&As[buf][sr][sc]     = *(bf16x8*)&ta[0];
        *(bf16x8*)&As[buf][sr][sc + 8] = *(bf16x8*)&ta[8];
        *(uint4*)&Bs[buf][sr][sc]      = tb0;
        *(uint4*)&Bs[buf][sr][sc + 8]  = tb1;
    };

    loadAB(0);
    storeLDS(0);
    __syncthreads();

    for (int kt = 0; kt < nk; kt++) {
        const int cur = kt & 1;
        if (kt + 1 < nk) loadAB(kt + 1);          // prefetch next chunk

        bf16x8 af[4], bfr[4];
        #pragma unroll
        for (int i = 0; i < 4; i++)
            af[i] = *(const bf16x8*)&As[cur][wm + i * 16 + l16][quad * 8];
        #pragma unroll
        for (int j = 0; j < 4; j++)
            bfr[j] = *(const bf16x8*)&Bs[cur][wn + j * 16 + l16][quad * 8];
        #pragma unroll
        for (int i = 0; i < 4; i++)
            #pragma unroll
            for (int j = 0; j < 4; j++)
                acc[i][j] = __builtin_amdgcn_mfma_f32_16x16x32_bf16(
                    bfr[j], af[i], acc[i][j], 0, 0, 0);   // swapped operands

        if (kt + 1 < nk) {
            storeLDS(cur ^ 1);
            __syncthreads();
        }
    }

    // bias: 4 consecutive cols per acc reg group
    float4 bj[4];
    #pragma unroll
    for (int j = 0; j < 4; j++)
        bj[j] = *(const float4*)&bias[n0 + wn + j * 16 + quad * 4];

    if (SPLITK > 1) {
        const float bscale = (blockIdx.z == 0) ? 1.0f : 0.0f;
        #pragma unroll
        for (int i = 0; i < 4; i++) {
            const long gr = m0 + wm + i * 16 + l16;
            if (gr < M) {
                #pragma unroll
                for (int j = 0; j < 4; j++) {
                    float* cp = (float*)Cout + gr * N + n0 + wn + j * 16 + quad * 4;
                    atomicAdd(cp + 0, acc[i][j][0] + bscale * bj[j].x);
                    atomicAdd(cp + 1, acc[i][j][1] + bscale * bj[j].y);
                    atomicAdd(cp + 2, acc[i][j][2] + bscale * bj[j].z);
                    atomicAdd(cp + 3, acc[i][j][3] + bscale * bj[j].w);
                }
            }
        }
        return;
    }

    #pragma unroll
    for (int i = 0; i < 4; i++) {
        const long gr = m0 + wm + i * 16 + l16;
        if (gr < M) {
            #pragma unroll
            for (int j = 0; j < 4; j++) {
                float4 v;
                v.x = acc[i][j][0] + bj[j].x;
                v.y = acc[i][j][1] + bj[j].y;
                v.z = acc[i][j][2] + bj[j].z;
                v.w = acc[i][j][3] + bj[j].w;
                if (RELU) {
                    v.x = fmaxf(v.x, 0.f); v.y = fmaxf(v.y, 0.f);
                    v.z = fmaxf(v.z, 0.f); v.w = fmaxf(v.w, 0.f);
                }
                const int gc = n0 + wn + j * 16 + quad * 4;
                if (OUTBF) {
                    unsigned short o[4] = {f2bf(v.x), f2bf(v.y), f2bf(v.z), f2bf(v.w)};
                    *(uint2*)((unsigned short*)Cout + gr * N + gc) = *(uint2*)o;
                } else {
                    *(float4*)((float*)Cout + gr * N + gc) = v;
                }
            }
        }
    }
}

// ---------------------------------------------------------------------------
// MFMA self-attention. Grid (5 q-tiles, 128 b*h). Block = 256 thr = 4 waves;
// wave w owns q-rows [q0+16w, q0+16w+16).
// ---------------------------------------------------------------------------
__global__ __launch_bounds__(256) void attn_kernel(
    const float* __restrict__ qkv, float* __restrict__ sa)
{
    __shared__ union {
        struct {
            unsigned short Ks[304][40];   // 24,320 B
            unsigned short Qs[64][40];    //  5,120 B
        } s;
        unsigned short Ps[4][16][328];    // 41,984 B
    } u;
    __shared__ unsigned short Vt[32][328]; // 20,992 B  (total 62,976 B)

    const int bh = blockIdx.y;            // b*8 + h
    const int b  = bh >> 3, h = bh & 7;
    const int q0 = blockIdx.x * 64;
    const int t  = threadIdx.x;

    for (int idx = t; idx < 304 * 8; idx += 256) {
        const int r = idx >> 3, c4 = (idx & 7) << 2;
        if (r < NQ) {
            const float4 kv = *(const float4*)(qkv + ((long)(b * NQ + r)) * 768 + 256 + h * 32 + c4);
            u.s.Ks[r][c4 + 0] = f2bf(kv.x); u.s.Ks[r][c4 + 1] = f2bf(kv.y);
            u.s.Ks[r][c4 + 2] = f2bf(kv.z); u.s.Ks[r][c4 + 3] = f2bf(kv.w);
        } else {
            u.s.Ks[r][c4 + 0] = 0; u.s.Ks[r][c4 + 1] = 0;
            u.s.Ks[r][c4 + 2] = 0; u.s.Ks[r][c4 + 3] = 0;
        }
    }
    for (int idx = t; idx < NQ * 8; idx += 256) {
        const int key = idx >> 3, dq = (idx & 7) << 2;
        const float4 vv = *(const float4*)(qkv + ((long)(b * NQ + key)) * 768 + 512 + h * 32 + dq);
        Vt[dq + 0][key] = f2bf(vv.x); Vt[dq + 1][key] = f2bf(vv.y);
        Vt[dq + 2][key] = f2bf(vv.z); Vt[dq + 3][key] = f2bf(vv.w);
    }
    for (int idx = t; idx < 32 * 20; idx += 256)   // zero keys 300..319
        Vt[idx / 20][300 + idx % 20] = 0;
    for (int idx = t; idx < 64 * 8; idx += 256) {
        const int r = idx >> 3, c4 = (idx & 7) << 2;
        const int q = q0 + r;
        if (q < NQ) {
            const float4 qv = *(const float4*)(qkv + ((long)(b * NQ + q)) * 768 + h * 32 + c4);
            u.s.Qs[r][c4 + 0] = f2bf(qv.x); u.s.Qs[r][c4 + 1] = f2bf(qv.y);
            u.s.Qs[r][c4 + 2] = f2bf(qv.z); u.s.Qs[r][c4 + 3] = f2bf(qv.w);
        } else {
            u.s.Qs[r][c4 + 0] = 0; u.s.Qs[r][c4 + 1] = 0;
            u.s.Qs[r][c4 + 2] = 0; u.s.Qs[r][c4 + 3] = 0;
        }
    }
    __syncthreads();

    const int wave = t >> 6, lane = t & 63;
    const int l16 = lane & 15, quad = lane >> 4;
    const float scale = 0.1767766952966369f;   // 1/sqrt(32)

    const bf16x8 aq = *(const bf16x8*)&u.s.Qs[wave * 16 + l16][quad * 8];
    f32x4 sacc[19];
    #pragma unroll
    for (int kt = 0; kt < 19; kt++) {
        const bf16x8 bk = *(const bf16x8*)&u.s.Ks[kt * 16 + l16][quad * 8];
        sacc[kt] = __builtin_amdgcn_mfma_f32_16x16x32_bf16(
            aq, bk, (f32x4){0.f, 0.f, 0.f, 0.f}, 0, 0, 0);
    }

    float inv[4];
    #pragma unroll
    for (int r = 0; r < 4; r++) {
        float m = -1e30f;
        #pragma unroll
        for (int kt = 0; kt < 19; kt++) {
            float s = sacc[kt][r] * scale;
            if (kt == 18 && l16 >= 12) s = -1e30f;    // keys 300..303 invalid
            sacc[kt][r] = s;
            m = fmaxf(m, s);
        }
        m = fmaxf(m, __shfl_xor(m, 1)); m = fmaxf(m, __shfl_xor(m, 2));
        m = fmaxf(m, __shfl_xor(m, 4)); m = fmaxf(m, __shfl_xor(m, 8));
        float sum = 0.f;
        #pragma unroll
        for (int kt = 0; kt < 19; kt++) {
            float p = __expf(sacc[kt][r] - m);
            sacc[kt][r] = p;
            sum += p;
        }
        sum += __shfl_xor(sum, 1); sum += __shfl_xor(sum, 2);
        sum += __shfl_xor(sum, 4); sum += __shfl_xor(sum, 8);
        inv[r] = 1.0f / sum;
    }

    __syncthreads();   // all waves done with Ks/Qs before Ps overwrites them

    #pragma unroll
    for (int kt = 0; kt < 19; kt++)
        #pragma unroll
        for (int r = 0; r < 4; r++)
            u.Ps[wave][quad * 4 + r][kt * 16 + l16] = f2bf(sacc[kt][r] * inv[r]);
    #pragma unroll
    for (int r = 0; r < 4; r++)      // zero pad keys 304..319
        u.Ps[wave][quad * 4 + r][304 + l16] = 0;

    f32x4 o0 = {0.f, 0.f, 0.f, 0.f}, o1 = {0.f, 0.f, 0.f, 0.f};
    #pragma unroll
    for (int kt = 0; kt < 10; kt++) {
        const bf16x8 ap  = *(const bf16x8*)&u.Ps[wave][l16][kt * 32 + quad * 8];
        const bf16x8 bv0 = *(const bf16x8*)&Vt[l16][kt * 32 + quad * 8];
        const bf16x8 bv1 = *(const bf16x8*)&Vt[16 + l16][kt * 32 + quad * 8];
        o0 = __builtin_amdgcn_mfma_f32_16x16x32_bf16(ap, bv0, o0, 0, 0, 0);
        o1 = __builtin_amdgcn_mfma_f32_16x16x32_bf16(ap, bv1, o1, 0, 0, 0);
    }

    #pragma unroll
    for (int r = 0; r < 4; r++) {
        const int q = q0 + wave * 16 + quad * 4 + r;
        if (q < NQ) {
            float* op = sa + ((long)(b * NQ + q)) * ND + h * 32;
            op[l16]      = o0[r];
            op[16 + l16] = o1[r];
        }
    }
}

// ---------------------------------------------------------------------------
// Residual + LayerNorm: one wave per row of 256.
// ---------------------------------------------------------------------------
__global__ __launch_bounds__(256) void residual_ln(
    const float* __restrict__ a, const float* __restrict__ r,
    const float* __restrict__ gam, const float* __restrict__ bet,
    float* __restrict__ out)
{
    const int row  = blockIdx.x * 4 + (threadIdx.x >> 6);
    const int lane = threadIdx.x & 63;
    const long base = (long)row * ND + lane * 4;
    float4 av = *(const float4*)(a + base);
    float4 rv = *(const float4*)(r + base);
    float x0 = av.x + rv.x, x1 = av.y + rv.y, x2 = av.z + rv.z, x3 = av.w + rv.w;
    float s  = x0 + x1 + x2 + x3;
    float s2 = x0 * x0 + x1 * x1 + x2 * x2 + x3 * x3;
    #pragma unroll
    for (int off = 32; off >= 1; off >>= 1) {
        s  += __shfl_xor(s, off);
        s2 += __shfl_xor(s2, off);
    }
    float mean = s * 0.00390625f;
    float var  = s2 * 0.00390625f - mean * mean;
    float rstd = rsqrtf(var + 1e-5f);
    float4 gv = *(const float4*)(gam + lane * 4);
    float4 bv = *(const float4*)(bet + lane * 4);
    float4 o;
    o.x = (x0 - mean) * rstd * gv.x + bv.x;
    o.y = (x1 - mean) * rstd * gv.y + bv.y;
    o.z = (x2 - mean) * rstd * gv.z + bv.z;
    o.w = (x3 - mean) * rstd * gv.w + bv.w;
    *(float4*)(out + base) = o;
}

// ---------------------------------------------------------------------------
// meta from head-GEMM result res[4800][128].
// ---------------------------------------------------------------------------
__global__ __launch_bounds__(256) void meta_kernel(
    const float* __restrict__ res, float* __restrict__ meta)
{
    const int t   = threadIdx.x;
    const int row = blockIdx.x * 8 + (t >> 5);
    const int s   = t & 31;
    const int h   = s >> 2;
    const float* rp = res + (long)row * 128;
    const float rx = 1.f / (1.f + __expf(-rp[0]));
    const float ry = 1.f / (1.f + __expf(-rp[1]));
    const float offx = rp[2 + 2 * s], offy = rp[3 + 2 * s];
    const float a0 = rp[66 + h * 4 + 0], a1 = rp[66 + h * 4 + 1];
    const float a2 = rp[66 + h * 4 + 2], a3 = rp[66 + h * 4 + 3];
    const float mx = fmaxf(fmaxf(a0, a1), fmaxf(a2, a3));
    const float den = __expf(a0 - mx) + __expf(a1 - mx) +
                      __expf(a2 - mx) + __expf(a3 - mx);
    const float awt = __expf(rp[66 + s] - mx) / den;

    const float lx = fminf(fmaxf(rx + offx, 0.f), 1.f) * (NWG - 1);
    const float ly = fminf(fmaxf(ry + offy, 0.f), 1.f) * (NWG - 1);
    const float fx = floorf(lx), fy = floorf(ly);
    int x0 = (int)fx; x0 = min(max(x0, 0), NWG - 1);
    int y0 = (int)fy; y0 = min(max(y0, 0), NWG - 1);
    const int x1 = min(x0 + 1, NWG - 1);
    const int y1 = min(y0 + 1, NWG - 1);
    const float wx1 = lx - fx, wx0 = 1.f - wx1;
    const float wy1 = ly - fy, wy0 = 1.f - wy1;
    float4 m0, m1;
    m0.x = __int_as_float(y0 * NWG + x0);
    m0.y = __int_as_float(y0 * NWG + x1);
    m0.z = __int_as_float(y1 * NWG + x0);
    m0.w = __int_as_float(y1 * NWG + x1);
    m1.x = awt * wx0 * wy0;
    m1.y = awt * wx1 * wy0;
    m1.z = awt * wx0 * wy1;
    m1.w = awt * wx1 * wy1;
    float* mp = meta + (long)row * 256 + s * 8;
    *(float4*)mp       = m0;
    *(float4*)(mp + 4) = m1;
}

// ---------------------------------------------------------------------------
// Deformable gather: block per (b,q); thread (h = t>>5, d = t&31).
// ---------------------------------------------------------------------------
__global__ __launch_bounds__(256) void deform_gather(
    const float* __restrict__ meta, const unsigned short* __restrict__ vals,
    float* __restrict__ ca)
{
    const int row = blockIdx.x;           // b*300+q
    const int b = row / NQ;
    __shared__ float ms[256];
    const int t = threadIdx.x;
    ms[t] = meta[(long)row * 256 + t];
    __syncthreads();
    const int h = t >> 5, d = t & 31;
    const unsigned short* vb = vals + (long)b * NHW * ND + h * 32 + d;
    float acc = 0.f;
    #pragma unroll
    for (int p = 0; p < NP; p++) {
        const float* mp = ms + h * 32 + p * 8;
        const int i00 = __float_as_int(mp[0]);
        const int i01 = __float_as_int(mp[1]);
        const int i10 = __float_as_int(mp[2]);
        const int i11 = __float_as_int(mp[3]);
        acc += mp[4] * bf2f(vb[(long)i00 * ND]);
        acc += mp[5] * bf2f(vb[(long)i01 * ND]);
        acc += mp[6] * bf2f(vb[(long)i10 * ND]);
        acc += mp[7] * bf2f(vb[(long)i11 * ND]);
    }
    ca[(long)row * ND + t] = acc;
}

// ---------------------------------------------------------------------------
extern "C" void kernel_launch(void* const* d_in, const int* in_sizes, int n_in,
                              void* d_out, int out_size, void* d_ws, size_t ws_size,
                              hipStream_t stream)
{
    (void)in_sizes; (void)n_in; (void)out_size; (void)ws_size;
    const float* tgt   = (const float*)d_in[0];
    const float* mem   = (const float*)d_in[1];
    const float* inpw  = (const float*)d_in[2];
    const float* inpb  = (const float*)d_in[3];
    const float* outw  = (const float*)d_in[4];
    const float* outb  = (const float*)d_in[5];
    const float* n1g   = (const float*)d_in[6];
    const float* n1b   = (const float*)d_in[7];
    const float* refw  = (const float*)d_in[8];
    const float* refb  = (const float*)d_in[9];
    const float* offw  = (const float*)d_in[10];
    const float* offb  = (const float*)d_in[11];
    const float* attww = (const float*)d_in[12];
    const float* attwb = (const float*)d_in[13];
    const float* vpw   = (const float*)d_in[14];
    const float* vpb   = (const float*)d_in[15];
    const float* opw   = (const float*)d_in[16];
    const float* opb   = (const float*)d_in[17];
    const float* n2g   = (const float*)d_in[18];
    const float* n2b   = (const float*)d_in[19];
    const float* l1w   = (const float*)d_in[20];
    const float* l1b   = (const float*)d_in[21];
    const float* l2w   = (const float*)d_in[22];
    const float* l2b   = (const float*)d_in[23];
    const float* n3g   = (const float*)d_in[24];
    const float* n3b   = (const float*)d_in[25];
    float* out = (float*)d_out;

    char* p = (char*)d_ws;
    auto alloc = [&](size_t bytes) {
        char* r = p; p += (bytes + 255) & ~(size_t)255; return (void*)r;
    };
    unsigned short* wtIn   = (unsigned short*)alloc(768 * 256 * 2);
    unsigned short* wtOut  = (unsigned short*)alloc(256 * 256 * 2);
    unsigned short* wtVp   = (unsigned short*)alloc(256 * 256 * 2);
    unsigned short* wtOp   = (unsigned short*)alloc(256 * 256 * 2);
    unsigned short* wtL1   = (unsigned short*)alloc(2048 * 256 * 2);
    unsigned short* wtL2   = (unsigned short*)alloc(256 * 2048 * 2);
    unsigned short* wtHead = (unsigned short*)alloc(128 * 256 * 2);
    float*          headb  = (float*)alloc(128 * 4);
    float* qkv  = (float*)alloc((size_t)NROW * 768 * 4);
    float* sa   = (float*)alloc((size_t)NROW * ND * 4);
    float* x1   = (float*)alloc((size_t)NROW * ND * 4);
    float* x2   = (float*)alloc((size_t)NROW * ND * 4);
    float* tmp  = (float*)alloc((size_t)NROW * ND * 4);
    float* ca   = (float*)alloc((size_t)NROW * ND * 4);
    float* meta = (float*)alloc((size_t)NROW * 256 * 4);
    void* uni = alloc((size_t)NB * NHW * ND * 2);   // vals bf16 / h1 fp32 alias
    unsigned short* vals = (unsigned short*)uni;
    float* h1 = (float*)uni;
    float* res = qkv;   // head-GEMM result [4800][128]; qkv is dead by then

    prep_weights<<<5761, 256, 0, stream>>>(
        inpw, outw, vpw, opw, l1w, l2w,
        refw, refb, offw, offb, attww, attwb,
        wtIn, wtOut, wtVp, wtOp, wtL1, wtL2, wtHead, headb);

    gemm_bt<0, 0, 1><<<dim3(6, 38), 256, 0, stream>>>(tgt, wtIn, inpb, qkv,
                                                      NROW, 768, 256);
    gemm_bt<0, 1, 1><<<dim3(2, 1250), 256, 0, stream>>>(mem, wtVp, vpb, vals,
                                                        NB * NHW, 256, 256);
    attn_kernel<<<dim3(5, 128), 256, 0, stream>>>(qkv, sa);
    gemm_bt<0, 0, 1><<<dim3(2, 38), 256, 0, stream>>>(sa, wtOut, outb, tmp,
                                                      NROW, 256, 256);
    residual_ln<<<1200, 256, 0, stream>>>(tgt, tmp, n1g, n1b, x1);
    gemm_bt<0, 0, 1><<<dim3(1, 38), 256, 0, stream>>>(x1, wtHead, headb, res,
                                                      NROW, 128, 256);
    meta_kernel<<<600, 256, 0, stream>>>(res, meta);
    deform_gather<<<4800, 256, 0, stream>>>(meta, vals, ca);
    gemm_bt<0, 0, 1><<<dim3(2, 38), 256, 0, stream>>>(ca, wtOp, opb, tmp,
                                                      NROW, 256, 256);
    residual_ln<<<1200, 256, 0, stream>>>(x1, tmp, n2g, n2b, x2);
    gemm_bt<1, 0, 1><<<dim3(16, 38), 256, 0, stream>>>(x2, wtL1, l1b, h1,
                                                       NROW, 2048, 256);
    hipMemsetAsync(tmp, 0, (size_t)NROW * ND * 4, stream);
    gemm_bt<0, 0, 4><<<dim3(2, 38, 4), 256, 0, stream>>>(h1, wtL2, l2b, tmp,
                                                         NROW, 256, 2048);
    residual_ln<<<1200, 256, 0, stream>>>(x2, tmp, n3g, n3b, out);
}